// Round 14
// baseline (378.922 us; speedup 1.0000x reference)
//
#include <hip/hip_runtime.h>
#include <hip/hip_fp16.h>
#include <math.h>

// ---- ws layout (bytes) ----
// contribH (fp16): [0, 25,886,720) as [v<5056][w*512+c]
// feat:     [25,886,720, +8,552,448) -> ends 34,439,168
// dedup:    @34,439,168: flags[2048] (+0), nUsed (+8192), list[2048] (+8448) -> ends +16,640
// A_h  fp16 [5056][320] @34,459,648 (3,235,840) -> ends 37,695,488   (contrib GEMM, dead after)
// B_h  fp16 [2560][320] @37,695,488 (1,638,400) -> ends 39,333,888   (contrib GEMM, dead after)
// B_hp fp16 [2][512][512] @39,333,888 (1,048,576) -> ends 40,382,464 (proj GEMM)
// WhhH fp16 [2][512][128] @40,382,464 (262,144) -> ends 40,644,608   (recurrence weights)
// A_hp fp16 [4224][512] @34,459,648 (4,325,376) -> ends 38,785,024   (proj GEMM; reuses dead A_h/B_h)
// post-conv aliases (contrib dead after convs):
//   preAll @2,097,152 (-> 19,202,048),
//   hT @19,202,048  hB @21,299,200  hC @23,396,352  (each 2,097,152, fp32)
//   hD @25,493,504 (32,768, fp32)   pOut @25,526,272 (32,768, fp64)  -> ends 25,559,040
#define DEDUP_B 34439168ULL
#define AH_B    34459648ULL
#define BH_B    37695488ULL
#define BHP_B   39333888ULL
#define WHH_B   40382464ULL
#define AHP_B   34459648ULL

typedef _Float16 half8 __attribute__((ext_vector_type(8)));
typedef float f32x4 __attribute__((ext_vector_type(4)));

__device__ inline void add8(float* a, float4 r){
  const __half2* h = (const __half2*)&r;
  #pragma unroll
  for (int q = 0; q < 4; ++q){
    float2 f = __half22float2(h[q]);
    a[2*q]   += f.x;
    a[2*q+1] += f.y;
  }
}

// ---------------- fused prep: out-zero + dedup-zero + featDoc-zero + embH + wTh + wihH + whhH ----------------
// all segments are independent writes (no cross-segment reads) -> single launch, grid-stride
__global__ __launch_bounds__(256) void k_prep(unsigned int* __restrict__ out32, int n,
                                              unsigned int* __restrict__ dd32,
                                              float* __restrict__ featDoc,
                                              const float* __restrict__ emb, _Float16* __restrict__ A_h,
                                              const float* __restrict__ convw, _Float16* __restrict__ B_h,
                                              const float* __restrict__ WihF, const float* __restrict__ WihB,
                                              _Float16* __restrict__ B_hp,
                                              const float* __restrict__ WhhF, const float* __restrict__ WhhB,
                                              _Float16* __restrict__ WhhH){
  const long o0 = n;                    // out zero
  const long o1 = o0 + 2112;            // dedup flags + nUsed (+pad)
  const long o2 = o1 + 512;             // featDoc
  const long o3 = o2 + 1617920;         // embH  (5056*320)
  const long o4 = o3 + 819200;          // wTh   (2560*320)
  const long o5 = o4 + 524288;          // wihH  (2*512*512)
  const long o6 = o5 + 131072;          // whhH  (2*512*128)
  for (long t = (long)blockIdx.x * 256 + threadIdx.x; t < o6; t += (long)gridDim.x * 256){
    if (t < o0){
      out32[t] = 0u;
    } else if (t < o1){
      dd32[t - o0] = 0u;
    } else if (t < o2){
      featDoc[t - o1] = 0.f;            // atomicMax target (relu floor 0)
    } else if (t < o3){
      long u = t - o2;
      int row = (int)(u / 320), col = (int)(u - (long)row * 320);
      float v = (row < 5053 && col < 300) ? emb[(size_t)row * 300 + col] * 1024.f : 0.f;
      A_h[u] = (_Float16)v;
    } else if (t < o4){
      long u = t - o3;
      int nn = (int)(u / 320), k = (int)(u - (long)nn * 320);
      int w = nn >> 9, c = nn & 511;
      float v = (k < 300) ? convw[((size_t)c * 300 + k) * 5 + w] : 0.f;
      B_h[u] = (_Float16)v;
    } else if (t < o5){
      long u = t - o4;
      int dir = (int)(u >> 18), r = (int)(u & 262143);
      B_hp[u] = (_Float16)((dir ? WihB : WihF)[r]);
    } else {
      long u = t - o5;
      int dir = (int)(u >> 16), r = (int)(u & 65535);
      WhhH[u] = (_Float16)((dir ? WhhB : WhhF)[r]);
    }
  }
}

// ---------------- mark used entities ----------------
__global__ __launch_bounds__(256) void k_mark(const int* __restrict__ cand, int* __restrict__ flags){
  int t = blockIdx.x * 256 + threadIdx.x;     // 2048 threads
  flags[cand[t]] = 1;
}

// ---------------- compact used entities into list ----------------
__global__ __launch_bounds__(256) void k_compact(const int* __restrict__ flags,
                                                 int* __restrict__ nUsed, int* __restrict__ list){
  int t = blockIdx.x * 256 + threadIdx.x;     // 2048 threads
  if (flags[t]){
    int s = atomicAdd(nUsed, 1);
    list[s] = t;
  }
}

// ---------------- contrib GEMM via fp16 MFMA: C[5056][2560] = A_h * B_h^T ----------------
// block = 4 waves (2x2); block tile 64x128; wave tile 32x64 = 2x4 frags 16x16; K = 10x32
__global__ __launch_bounds__(256) void k_contrib(const _Float16* __restrict__ A_h,
                                                 const _Float16* __restrict__ B_h,
                                                 __half* __restrict__ contrib){
  int tid = threadIdx.x;
  int lane = tid & 63, wid = tid >> 6;
  int wr = wid >> 1, wc = wid & 1;
  int m0 = blockIdx.x * 64 + wr * 32;          // 79 tiles -> rows < 5056
  int n0 = blockIdx.y * 128 + wc * 64;         // 20 tiles -> cols < 2560
  int lr = lane & 15, lk = (lane >> 4) * 8;

  const _Float16* Ap = A_h + (size_t)(m0 + lr) * 320 + lk;      // + fr*16*320 + kk
  const _Float16* Bp = B_h + (size_t)(n0 + lr) * 320 + lk;      // + fc*16*320 + kk

  f32x4 acc[2][4];
  #pragma unroll
  for (int fr = 0; fr < 2; ++fr)
    #pragma unroll
    for (int fc = 0; fc < 4; ++fc) acc[fr][fc] = (f32x4){0.f, 0.f, 0.f, 0.f};

  for (int kk = 0; kk < 320; kk += 32){
    half8 a0 = *(const half8*)(Ap + kk);
    half8 a1 = *(const half8*)(Ap + 16 * 320 + kk);
    half8 b0 = *(const half8*)(Bp + kk);
    half8 b1 = *(const half8*)(Bp + 16 * 320 + kk);
    half8 b2 = *(const half8*)(Bp + 32 * 320 + kk);
    half8 b3 = *(const half8*)(Bp + 48 * 320 + kk);
    acc[0][0] = __builtin_amdgcn_mfma_f32_16x16x32_f16(a0, b0, acc[0][0], 0, 0, 0);
    acc[0][1] = __builtin_amdgcn_mfma_f32_16x16x32_f16(a0, b1, acc[0][1], 0, 0, 0);
    acc[0][2] = __builtin_amdgcn_mfma_f32_16x16x32_f16(a0, b2, acc[0][2], 0, 0, 0);
    acc[0][3] = __builtin_amdgcn_mfma_f32_16x16x32_f16(a0, b3, acc[0][3], 0, 0, 0);
    acc[1][0] = __builtin_amdgcn_mfma_f32_16x16x32_f16(a1, b0, acc[1][0], 0, 0, 0);
    acc[1][1] = __builtin_amdgcn_mfma_f32_16x16x32_f16(a1, b1, acc[1][1], 0, 0, 0);
    acc[1][2] = __builtin_amdgcn_mfma_f32_16x16x32_f16(a1, b2, acc[1][2], 0, 0, 0);
    acc[1][3] = __builtin_amdgcn_mfma_f32_16x16x32_f16(a1, b3, acc[1][3], 0, 0, 0);
  }
  // C/D layout: col = lane&15, row = (lane>>4)*4 + r   (measured, dtype-independent)
  const float s = 1.f / 1024.f;
  #pragma unroll
  for (int fr = 0; fr < 2; ++fr){
    int row = m0 + fr * 16 + (lane >> 4) * 4;
    #pragma unroll
    for (int fc = 0; fc < 4; ++fc){
      int col = n0 + fc * 16 + lr;
      #pragma unroll
      for (int r = 0; r < 4; ++r)
        contrib[(size_t)(row + r) * 2560 + col] = __float2half(acc[fr][fc][r] * s);
    }
  }
}

// ---------------- char-CNN gather, merged title+body+ctx, XCD channel-split ----------------
// block ranges: [0,16384) title (L=32, list), [16384,32768) body (L=128, list),
// [32768,33280) ctx (L=128, direct). Segment bases are multiples of 8 -> g = b&7
// keeps the per-XCD 64-channel strip mapping (3.2 MB < 4 MB L2) intact.
__global__ __launch_bounds__(256) void k_conv(const int* __restrict__ title_v,
                                              const int* __restrict__ body_v,
                                              const int* __restrict__ ctx_v,
                                              const __half* __restrict__ contrib,
                                              const float* __restrict__ convb,
                                              float* __restrict__ featAll,
                                              const int* __restrict__ list,
                                              const int* __restrict__ nUsed){
  __shared__ int tok[128];
  __shared__ float red[256 * 9];      // padded stride 9 -> no bank conflict
  int bg = blockIdx.x, tid = threadIdx.x;
  const int* idx; int L, row0; bool useList;
  if (bg < 16384){ idx = title_v; L = 32;  row0 = 0;    useList = true; }
  else if (bg < 32768){ bg -= 16384; idx = body_v; L = 128; row0 = 2048; useList = true; }
  else { bg -= 32768; idx = ctx_v; L = 128; row0 = 4096; useList = false; }
  int g = bg & 7, sIdx = bg >> 3;
  int s = sIdx;
  if (useList){
    if (sIdx >= *nUsed) return;
    s = list[sIdx];
  }
  const int* row = idx + (size_t)s * L;
  for (int i = tid; i < L; i += 256) tok[i] = row[i];
  __syncthreads();
  int c8 = tid & 7;                   // channel octet within group
  int pg = tid >> 3;                  // position group 0..31
  int cOff = g * 64 + c8 * 8;         // absolute channel base (8 channels/thread)
  float bias[8], mx[8];
  {
    float4 b0 = *(const float4*)(convb + cOff);
    float4 b1 = *(const float4*)(convb + cOff + 4);
    bias[0]=b0.x; bias[1]=b0.y; bias[2]=b0.z; bias[3]=b0.w;
    bias[4]=b1.x; bias[5]=b1.y; bias[6]=b1.z; bias[7]=b1.w;
  }
  #pragma unroll
  for (int k = 0; k < 8; ++k) mx[k] = 0.f;     // relu floor folded into init
  int P = L - 4;
  int per = (P + 31) >> 5;
  int p = pg * per, pe = min(p + per, P);
  for (; p + 1 < pe; p += 2){         // 2 positions/iter -> 10 x 16B loads in flight
    float a0[8], a1[8];
    #pragma unroll
    for (int k = 0; k < 8; ++k){ a0[k] = bias[k]; a1[k] = bias[k]; }
    #pragma unroll
    for (int w = 0; w < 5; ++w){
      float4 r0 = *(const float4*)(contrib + ((size_t)tok[p + w] * 5 + w) * 512 + cOff);
      float4 r1 = *(const float4*)(contrib + ((size_t)tok[p + 1 + w] * 5 + w) * 512 + cOff);
      add8(a0, r0);
      add8(a1, r1);
    }
    #pragma unroll
    for (int k = 0; k < 8; ++k) mx[k] = fmaxf(mx[k], fmaxf(a0[k], a1[k]));
  }
  if (p < pe){                        // odd tail
    float a0[8];
    #pragma unroll
    for (int k = 0; k < 8; ++k) a0[k] = bias[k];
    #pragma unroll
    for (int w = 0; w < 5; ++w){
      float4 r0 = *(const float4*)(contrib + ((size_t)tok[p + w] * 5 + w) * 512 + cOff);
      add8(a0, r0);
    }
    #pragma unroll
    for (int k = 0; k < 8; ++k) mx[k] = fmaxf(mx[k], a0[k]);
  }
  #pragma unroll
  for (int k = 0; k < 8; ++k) red[tid * 9 + k] = mx[k];
  __syncthreads();
  if (tid < 64){                      // thread t reduces channel g*64+t over 32 pos-groups
    int c8r = tid >> 3, kr = tid & 7;
    float o = red[c8r * 9 + kr];
    #pragma unroll
    for (int q = 1; q < 32; ++q)
      o = fmaxf(o, red[(q * 8 + c8r) * 9 + kr]);
    featAll[(size_t)(row0 + s) * 512 + g * 64 + tid] = o;
  }
}

// ---------------- doc conv (fp16 table): 32 blocks x 16 positions, atomicMax merge ----------------
__global__ __launch_bounds__(256) void k_conv_doc(const int* __restrict__ doc,
                                                  const __half* __restrict__ contrib,
                                                  const float* __restrict__ convb,
                                                  float* __restrict__ featDoc){
  __shared__ int tok[512];
  __shared__ float red[256 * 9];
  int b = blockIdx.x, tid = threadIdx.x;
  for (int i = tid; i < 512; i += 256) tok[i] = doc[i];
  __syncthreads();
  int c8 = tid & 63, pg = tid >> 6;
  float bias[8], mx[8];
  {
    float4 b0 = *(const float4*)(convb + c8 * 8);
    float4 b1 = *(const float4*)(convb + c8 * 8 + 4);
    bias[0]=b0.x; bias[1]=b0.y; bias[2]=b0.z; bias[3]=b0.w;
    bias[4]=b1.x; bias[5]=b1.y; bias[6]=b1.z; bias[7]=b1.w;
  }
  #pragma unroll
  for (int k = 0; k < 8; ++k) mx[k] = 0.f;
  int p0 = b * 16, p1 = min(p0 + 16, 508);
  int n = p1 - p0;
  int per = (n + 3) >> 2;
  int p = p0 + pg * per, pe = min(p + per, p1);
  for (; p < pe; ++p){
    float a0[8];
    #pragma unroll
    for (int k = 0; k < 8; ++k) a0[k] = bias[k];
    #pragma unroll
    for (int w = 0; w < 5; ++w){
      float4 r0 = *(const float4*)(contrib + ((size_t)tok[p + w] * 5 + w) * 512 + c8 * 8);
      add8(a0, r0);
    }
    #pragma unroll
    for (int k = 0; k < 8; ++k) mx[k] = fmaxf(mx[k], a0[k]);
  }
  #pragma unroll
  for (int k = 0; k < 8; ++k) red[tid * 9 + k] = mx[k];
  __syncthreads();
  if (tid < 64){
    #pragma unroll
    for (int k = 0; k < 8; ++k){
      float o = fmaxf(fmaxf(red[tid * 9 + k], red[(tid + 64) * 9 + k]),
                      fmaxf(red[(tid + 128) * 9 + k], red[(tid + 192) * 9 + k]));
      // values >= 0 -> IEEE order == int order
      atomicMax((int*)(featDoc + tid * 8 + k), __float_as_int(o));
    }
  }
}

// ---------------- feat -> fp16 A_hp[4224][512], scaled by 2^10 ----------------
__global__ __launch_bounds__(256) void k_featH(const float* __restrict__ feat, _Float16* __restrict__ A_hp){
  int t = blockIdx.x * 256 + threadIdx.x;      // < 4224*512 = 2,162,688
  if (t >= 4224 * 512) return;
  int row = t >> 9;
  float v = (row < 4161) ? feat[t] * 1024.f : 0.f;   // rows >= 4161 never written by convs
  A_hp[t] = (_Float16)v;
}

// ---------------- input projection via fp16 MFMA: preAll[dir] = A_hp * B_hp[dir]^T + bias ----------------
// block = 4 waves (2x2); block tile 64x128; wave tile 32x64 = 2x4 frags 16x16; K = 16x32
__global__ __launch_bounds__(256) void k_proj(const _Float16* __restrict__ A_hp,
                                              const _Float16* __restrict__ B_hp,
                                              const float* __restrict__ bihF, const float* __restrict__ bhhF,
                                              const float* __restrict__ bihB, const float* __restrict__ bhhB,
                                              float* __restrict__ preAll){
  int tid = threadIdx.x;
  int lane = tid & 63, wid = tid >> 6;
  int wr = wid >> 1, wc = wid & 1;
  int dir = blockIdx.z;
  int m0 = blockIdx.x * 64 + wr * 32;          // 66 tiles -> rows < 4224
  int n0 = blockIdx.y * 128 + wc * 64;         // 4 tiles -> cols < 512
  int lr = lane & 15, lk = (lane >> 4) * 8;

  const _Float16* Ap = A_hp + (size_t)(m0 + lr) * 512 + lk;
  const _Float16* Bp = B_hp + (size_t)dir * 262144 + (size_t)(n0 + lr) * 512 + lk;

  f32x4 acc[2][4];
  #pragma unroll
  for (int fr = 0; fr < 2; ++fr)
    #pragma unroll
    for (int fc = 0; fc < 4; ++fc) acc[fr][fc] = (f32x4){0.f, 0.f, 0.f, 0.f};

  for (int kk = 0; kk < 512; kk += 32){
    half8 a0 = *(const half8*)(Ap + kk);
    half8 a1 = *(const half8*)(Ap + 16 * 512 + kk);
    half8 b0 = *(const half8*)(Bp + kk);
    half8 b1 = *(const half8*)(Bp + 16 * 512 + kk);
    half8 b2 = *(const half8*)(Bp + 32 * 512 + kk);
    half8 b3 = *(const half8*)(Bp + 48 * 512 + kk);
    acc[0][0] = __builtin_amdgcn_mfma_f32_16x16x32_f16(a0, b0, acc[0][0], 0, 0, 0);
    acc[0][1] = __builtin_amdgcn_mfma_f32_16x16x32_f16(a0, b1, acc[0][1], 0, 0, 0);
    acc[0][2] = __builtin_amdgcn_mfma_f32_16x16x32_f16(a0, b2, acc[0][2], 0, 0, 0);
    acc[0][3] = __builtin_amdgcn_mfma_f32_16x16x32_f16(a0, b3, acc[0][3], 0, 0, 0);
    acc[1][0] = __builtin_amdgcn_mfma_f32_16x16x32_f16(a1, b0, acc[1][0], 0, 0, 0);
    acc[1][1] = __builtin_amdgcn_mfma_f32_16x16x32_f16(a1, b1, acc[1][1], 0, 0, 0);
    acc[1][2] = __builtin_amdgcn_mfma_f32_16x16x32_f16(a1, b2, acc[1][2], 0, 0, 0);
    acc[1][3] = __builtin_amdgcn_mfma_f32_16x16x32_f16(a1, b3, acc[1][3], 0, 0, 0);
  }
  const float s = 1.f / 1024.f;
  const float* bih = dir ? bihB : bihF;
  const float* bhh = dir ? bhhB : bhhF;
  float* outp = preAll + (size_t)dir * 4176 * 512;
  #pragma unroll
  for (int fr = 0; fr < 2; ++fr){
    int row = m0 + fr * 16 + (lane >> 4) * 4;
    #pragma unroll
    for (int fc = 0; fc < 4; ++fc){
      int col = n0 + fc * 16 + lr;
      float bias = bih[col] + bhh[col];
      #pragma unroll
      for (int r = 0; r < 4; ++r)
        if (row + r < 4176)
          outp[(size_t)(row + r) * 512 + col] = acc[fr][fc][r] * s + bias;
    }
  }
}

// ---------------- LSTM recurrence v9: v8 + all-lane redundant cell update ----------------
// v8 measured: 71.9 us, VGPR 84, no spill; latency-bound on the per-step chain.
// v9: each lane loads ALL FOUR gate preacts (same values across the 4-lane group) so
// after the butterfly every lane holds complete p0..p3 AND pf0..pf3 -> computes the
// whole cell update redundantly. Removes the 3 activation-gather shuffles and the
// divergent kc==0 tail from the critical path. Formulas/order unchanged -> lanes
// agree bit-exactly; only lane kc==0 stores.
__global__ __launch_bounds__(512, 2) void k_recur(const float* __restrict__ preAll,
                                                  const _Float16* __restrict__ WhhH,
                                                  const int* __restrict__ cand,
                                                  float* __restrict__ hT, float* __restrict__ hB,
                                                  float* __restrict__ hC, float* __restrict__ hD){
  int c = blockIdx.x, dir = blockIdx.y, tid = threadIdx.x;
  int lstm = (c < 64) ? 0 : (c < 128) ? 1 : (c < 192) ? 2 : 3;
  int b = (lstm == 3) ? 0 : (c - lstm * 64);
  const float* pre = preAll + (size_t)dir * 4176 * 512;
  float* hout;
  if (lstm == 0)      hout = hT + (size_t)b * 32 * 256;
  else if (lstm == 1) hout = hB + (size_t)b * 32 * 256;
  else if (lstm == 2) hout = hC + (size_t)b * 32 * 256;
  else                hout = hD;
  hout += dir * 128;

  int cidx = tid >> 2;                 // cell 0..127
  int kc = tid & 3;                    // k-chunk
  int k0 = kc * 32;

  // weights: gate m, halves k0..k0+31 -> wv[m][j] holds halves k0+8j..k0+8j+7
  half8 wv[4][4];                      // 64 VGPRs packed fp16
  #pragma unroll
  for (int m = 0; m < 4; ++m){
    const _Float16* wp = WhhH + (size_t)dir * 65536 + (size_t)(m * 128 + cidx) * 128 + k0;
    #pragma unroll
    for (int j = 0; j < 4; ++j)
      wv[m][j] = *(const half8*)(wp + j * 8);
  }
  {
    float* wf = (float*)wv;            // pin the 64 packed words (defeats remat; v6-proven)
    #pragma unroll
    for (int i = 0; i < 64; ++i)
      asm volatile("v_mov_b32 %0, %1" : "=v"(wf[i]) : "v"(wf[i]));
  }

  __shared__ __align__(16) float hpad[2][4][36];   // [buf][chunk][32+4 pad] bank-staggered
  __shared__ int candL[32];
  if (tid < 288) ((float*)hpad)[tid] = 0.f;
  if (lstm < 2 && tid < 32) candL[tid] = cand[b * 32 + tid];
  __syncthreads();

  // prefetch all 4 gate preacts for s=0 (same for all lanes of the 4-group)
  float pf0, pf1, pf2, pf3;
  {
    int t0 = dir ? 31 : 0;
    int rowi;
    if (lstm == 0)      rowi = candL[t0];
    else if (lstm == 1) rowi = 2048 + candL[t0];
    else if (lstm == 2) rowi = 4096 + b;
    else                rowi = 4160;
    const float* pr = pre + (size_t)rowi * 512 + cidx;
    pf0 = pr[0]; pf1 = pr[128]; pf2 = pr[256]; pf3 = pr[384];
  }

  float cst = 0.f;
  for (int s = 0; s < 32; ++s){
    int t = dir ? (31 - s) : s;
    int cur = s & 1, nxt = cur ^ 1;
    // issue next step's preact loads early (hide under matvec)
    float pn0 = 0.f, pn1 = 0.f, pn2 = 0.f, pn3 = 0.f;
    if (s < 31){
      int t2 = dir ? (31 - (s + 1)) : (s + 1);
      int rowi;
      if (lstm == 0)      rowi = candL[t2];
      else if (lstm == 1) rowi = 2048 + candL[t2];
      else if (lstm == 2) rowi = 4096 + b;
      else                rowi = 4160;
      const float* pr = pre + (size_t)rowi * 512 + cidx;
      pn0 = pr[0]; pn1 = pr[128]; pn2 = pr[256]; pn3 = pr[384];
    }
    // matvec partials: 4 gate cols x 32 k; fp16 weights, fp32 h
    float p0 = 0.f, p1 = 0.f, p2 = 0.f, p3 = 0.f;
    #pragma unroll
    for (int j = 0; j < 4; ++j){       // 8 k per j
      float4 ha = *(const float4*)&hpad[cur][kc][j * 8];
      float4 hb = *(const float4*)&hpad[cur][kc][j * 8 + 4];
      p0 += (float)wv[0][j][0] * ha.x + (float)wv[0][j][1] * ha.y
          + (float)wv[0][j][2] * ha.z + (float)wv[0][j][3] * ha.w
          + (float)wv[0][j][4] * hb.x + (float)wv[0][j][5] * hb.y
          + (float)wv[0][j][6] * hb.z + (float)wv[0][j][7] * hb.w;
      p1 += (float)wv[1][j][0] * ha.x + (float)wv[1][j][1] * ha.y
          + (float)wv[1][j][2] * ha.z + (float)wv[1][j][3] * ha.w
          + (float)wv[1][j][4] * hb.x + (float)wv[1][j][5] * hb.y
          + (float)wv[1][j][6] * hb.z + (float)wv[1][j][7] * hb.w;
      p2 += (float)wv[2][j][0] * ha.x + (float)wv[2][j][1] * ha.y
          + (float)wv[2][j][2] * ha.z + (float)wv[2][j][3] * ha.w
          + (float)wv[2][j][4] * hb.x + (float)wv[2][j][5] * hb.y
          + (float)wv[2][j][6] * hb.z + (float)wv[2][j][7] * hb.w;
      p3 += (float)wv[3][j][0] * ha.x + (float)wv[3][j][1] * ha.y
          + (float)wv[3][j][2] * ha.z + (float)wv[3][j][3] * ha.w
          + (float)wv[3][j][4] * hb.x + (float)wv[3][j][5] * hb.y
          + (float)wv[3][j][6] * hb.z + (float)wv[3][j][7] * hb.w;
    }
    // butterfly sum over the 4-lane group -> every lane has complete p0..p3
    p0 += __shfl_xor(p0, 1); p0 += __shfl_xor(p0, 2);
    p1 += __shfl_xor(p1, 1); p1 += __shfl_xor(p1, 2);
    p2 += __shfl_xor(p2, 1); p2 += __shfl_xor(p2, 2);
    p3 += __shfl_xor(p3, 1); p3 += __shfl_xor(p3, 2);
    // all lanes compute the full cell update redundantly (deterministic-identical)
    float si = 1.f / (1.f + __expf(-(p0 + pf0)));
    float sf = 1.f / (1.f + __expf(-(p1 + pf1)));
    float tg = tanhf(p2 + pf2);
    float so = 1.f / (1.f + __expf(-(p3 + pf3)));
    cst = sf * cst + si * tg;
    float hf = so * tanhf(cst);
    if (kc == 0){
      hpad[nxt][cidx >> 5][cidx & 31] = hf;
      hout[(size_t)t * 256 + cidx] = hf;
    }
    pf0 = pn0; pf1 = pn1; pf2 = pn2; pf3 = pn3;
    __syncthreads();
  }
}

// ---------------- BiDAF attention, one block per (mention, pass) ----------------
__global__ __launch_bounds__(256) void k_att1(const float* __restrict__ hC,
                                              const float* __restrict__ hT,
                                              const float* __restrict__ hD,
                                              const float* __restrict__ hB,
                                              const float* __restrict__ wc_g, const float* __restrict__ bc_g,
                                              const float* __restrict__ wq_g, const float* __restrict__ bq_g,
                                              const float* __restrict__ wcq_g, const float* __restrict__ bcq_g,
                                              const float* __restrict__ wz_g, const float* __restrict__ bz_g,
                                              double* __restrict__ pOut){
  int b = blockIdx.x, pass = blockIdx.y, tid = threadIdx.x;
  __shared__ float cS[32][260];     // stride 260: 16B-aligned stores, conflict-free reads
  __shared__ float qS[32][260];
  __shared__ float wS[7][256];      // wc, wq, wcq, wz0, wz1, wz2, wz3
  __shared__ double q2cS[256];
  __shared__ double cwS[32], qwS[32], qzS[32], paS[32], smaxS[32], bsmS[32];
  const float* cp = pass ? hD : (hC + (size_t)b * 8192);
  const float* qp = (pass ? hB : hT) + (size_t)b * 8192;
  for (int k = tid; k < 2048; k += 256){
    int i = k >> 6, d4 = (k & 63) * 4;
    *(float4*)&cS[i][d4] = *(const float4*)(cp + i * 256 + d4);
    *(float4*)&qS[i][d4] = *(const float4*)(qp + i * 256 + d4);
  }
  wS[0][tid] = wc_g[tid];
  wS[1][tid] = wq_g[tid];
  wS[2][tid] = wcq_g[tid];
  wS[3][tid] = wz_g[tid];
  wS[4][tid] = wz_g[256 + tid];
  wS[5][tid] = wz_g[512 + tid];
  wS[6][tid] = wz_g[768 + tid];
  __syncthreads();
  int i = tid >> 3, js = tid & 7;
  {
    double a = 0, aq = 0, az = 0;
    for (int k = 0; k < 32; ++k){
      int d = js * 32 + k;
      a  += (double)cS[i][d] * (double)wS[0][d];
      aq += (double)qS[i][d] * (double)wS[1][d];
      az += (double)qS[i][d] * (double)wS[4][d];
    }
    #pragma unroll
    for (int m = 1; m < 8; m <<= 1){
      a  += __shfl_xor(a, m);
      aq += __shfl_xor(aq, m);
      az += __shfl_xor(az, m);
    }
    if (js == 0){ cwS[i] = a; qwS[i] = aq; qzS[i] = az; }
  }
  __syncthreads();
  double bsum = (double)bc_g[0] + (double)bq_g[0] + (double)bcq_g[0];
  double sa[4] = {0,0,0,0}, ta[4] = {0,0,0,0};
  for (int d = 0; d < 256; ++d){
    double cd = (double)cS[i][d];
    double cw1 = cd * (double)wS[2][d];
    double cw2 = cd * (double)wS[5][d];
    #pragma unroll
    for (int m = 0; m < 4; ++m){
      double qv = (double)qS[js + m * 8][d];
      sa[m] += cw1 * qv;
      ta[m] += cw2 * qv;
    }
  }
  {
    double cwv = cwS[i];
    double s[4], mx = -1e300;
    #pragma unroll
    for (int m = 0; m < 4; ++m){
      s[m] = sa[m] + cwv + qwS[js + m * 8] + bsum;
      mx = fmax(mx, s[m]);
    }
    #pragma unroll
    for (int m = 1; m < 8; m <<= 1) mx = fmax(mx, __shfl_xor(mx, m));
    double esum = 0, eacc = 0;
    #pragma unroll
    for (int m = 0; m < 4; ++m){
      double e = exp(s[m] - mx);
      esum += e;
      eacc += e * (qzS[js + m * 8] + ta[m]);
    }
    #pragma unroll
    for (int m = 1; m < 8; m <<= 1){
      esum += __shfl_xor(esum, m);
      eacc += __shfl_xor(eacc, m);
    }
    if (js == 0){ paS[i] = eacc / esum; smaxS[i] = mx; }
  }
  __syncthreads();
  if (tid < 32){
    double v = smaxS[tid];
    double m2 = v;
    #pragma unroll
    for (int m = 1; m < 32; m <<= 1) m2 = fmax(m2, __shfl_xor(m2, m));
    double e = exp(v - m2), ssum = e;
    #pragma unroll
    for (int m = 1; m < 32; m <<= 1) ssum += __shfl_xor(ssum, m);
    bsmS[tid] = e / ssum;
  }
  __syncthreads();
  {
    double a = 0;
    for (int ii = 0; ii < 32; ++ii) a += bsmS[ii] * (double)cS[ii][tid];
    q2cS[tid] = a;
  }
  __syncthreads();
  {
    double t1 = 0, t4 = 0;
    for (int k = 0; k < 32; ++k){
      int d = js * 32 + k;
      double cd = (double)cS[i][d];
      t1 += cd * (double)wS[3][d];
      t4 += cd * q2cS[d] * (double)wS[6][d];
    }
    #pragma unroll
    for (int m = 1; m < 8; m <<= 1){
      t1 += __shfl_xor(t1, m);
      t4 += __shfl_xor(t4, m);
    }
    if (js == 0)
      pOut[((size_t)pass * 64 + b) * 32 + i] = t1 + paS[i] + t4 + (double)bz_g[0];
  }
}

// ---------------- combine p1/p2 -> score, softmax, scatter ----------------
__global__ __launch_bounds__(64) void k_att2(const double* __restrict__ pOut,
                                             const float* __restrict__ wp1_g, const float* __restrict__ bp1_g,
                                             const float* __restrict__ wp2_g, const float* __restrict__ bp2_g,
                                             const int* __restrict__ cand,
                                             float* __restrict__ out){
  int b = blockIdx.x, tid = threadIdx.x;
  if (tid >= 32) return;
  double p1 = pOut[(size_t)b * 32 + tid];
  double p2 = pOut[(size_t)(64 + b) * 32 + tid];
  double sc = (double)wp1_g[0] * p1 + (double)bp1_g[0]
            + (double)wp2_g[0] * p2 + (double)bp2_g[0];
  double mx = sc, rs = sc;
  #pragma unroll
  for (int m = 1; m < 32; m <<= 1){
    mx = fmax(mx, __shfl_xor(mx, m));
    rs += __shfl_xor(rs, m);
  }
  double e = exp(sc - mx), es = e;
  #pragma unroll
  for (int m = 1; m < 32; m <<= 1) es += __shfl_xor(es, m);
  int col = cand[b * 32 + tid];
  out[(size_t)b * 2048 + col] = (float)sc;
  out[131072 + (size_t)b * 2048 + col] = (float)(e / es);
  out[262144 + (size_t)b * 2048 + col] = (float)(sc / rs);
}

// ---------------------------------------------------------------------------
extern "C" void kernel_launch(void* const* d_in, const int* in_sizes, int n_in,
                              void* d_out, int out_size, void* d_ws, size_t ws_size,
                              hipStream_t stream) {
  const int* title_v = (const int*)d_in[0];
  const int* body_v  = (const int*)d_in[1];
  const int* ctx_v   = (const int*)d_in[3];
  const int* doc_v   = (const int*)d_in[4];
  const int* cand    = (const int*)d_in[5];
  const float* emb   = (const float*)d_in[6];
  const float* convw = (const float*)d_in[7];
  const float* convb = (const float*)d_in[8];
  const float* WihF  = (const float*)d_in[9];
  const float* WhhF  = (const float*)d_in[10];
  const float* bihF  = (const float*)d_in[11];
  const float* bhhF  = (const float*)d_in[12];
  const float* WihB  = (const float*)d_in[13];
  const float* WhhB  = (const float*)d_in[14];
  const float* bihB  = (const float*)d_in[15];
  const float* bhhB  = (const float*)d_in[16];
  float* out = (float*)d_out;

  const size_t CONTRIB_B = (size_t)5056 * 2560 * 2;     // 25,886,720 (fp16)
  char* base = (char*)d_ws;
  if (ws_size < 60325888) return;
  __half* contrib = (__half*)base;
  char* featBase = base + CONTRIB_B;                    // 25,886,720
  float* feat = (float*)featBase;
  float* featDoc = feat + (size_t)4160 * 512;

  // dedup buffers after feat (dead once convs complete)
  int* flags = (int*)(base + DEDUP_B);
  int* nUsed = (int*)(base + DEDUP_B + 8192);
  int* list  = (int*)(base + DEDUP_B + 8448);

  // fp16 GEMM / recurrence inputs
  _Float16* A_h  = (_Float16*)(base + AH_B);            // contrib GEMM A (dead after k_contrib)
  _Float16* B_h  = (_Float16*)(base + BH_B);            // contrib GEMM B (dead after k_contrib)
  _Float16* A_hp = (_Float16*)(base + AHP_B);           // proj GEMM A (reuses A_h/B_h space)
  _Float16* B_hp = (_Float16*)(base + BHP_B);           // proj GEMM B
  _Float16* WhhH = (_Float16*)(base + WHH_B);           // recurrence weights fp16

  // post-conv aliases (contrib dead after convs; feat/dedup dead after k_featH/k_proj)
  float*  preAll = (float*)(base + 2097152);            // -> 19,202,048
  float*  hT     = (float*)(base + 19202048);           // 2,097,152 each (fp32)
  float*  hB     = (float*)(base + 21299200);
  float*  hC     = (float*)(base + 23396352);
  float*  hD     = (float*)(base + 25493504);           // 32,768
  double* pOut   = (double*)(base + 25526272);          // 32,768 -> ends 25,559,040

  k_prep<<<4096, 256, 0, stream>>>((unsigned int*)out, out_size,
                                   (unsigned int*)(base + DEDUP_B), featDoc,
                                   emb, A_h, convw, B_h, WihF, WihB, B_hp,
                                   WhhF, WhhB, WhhH);
  k_mark<<<8, 256, 0, stream>>>(cand, flags);
  k_compact<<<8, 256, 0, stream>>>(flags, nUsed, list);
  k_contrib<<<dim3(79, 20), 256, 0, stream>>>(A_h, B_h, contrib);

  k_conv<<<33280, 256, 0, stream>>>(title_v, body_v, ctx_v, contrib, convb, feat, list, nUsed);
  k_conv_doc<<<32, 256, 0, stream>>>(doc_v, contrib, convb, featDoc);

  k_featH<<<8448, 256, 0, stream>>>(feat, A_hp);
  k_proj<<<dim3(66, 4, 2), 256, 0, stream>>>(A_hp, B_hp, bihF, bhhF, bihB, bhhB, preAll);
  k_recur<<<dim3(193, 2), 512, 0, stream>>>(preAll, WhhH, cand, hT, hB, hC, hD);
  k_att1<<<dim3(64, 2), 256, 0, stream>>>(hC, hT, hD, hB,
                                (const float*)d_in[17], (const float*)d_in[18],
                                (const float*)d_in[19], (const float*)d_in[20],
                                (const float*)d_in[21], (const float*)d_in[22],
                                (const float*)d_in[23], (const float*)d_in[24],
                                pOut);
  k_att2<<<64, 64, 0, stream>>>(pOut,
                                (const float*)d_in[25], (const float*)d_in[26],
                                (const float*)d_in[27], (const float*)d_in[28],
                                cand, out);
}

// Round 15
// 367.377 us; speedup vs baseline: 1.0314x; 1.0314x over previous
//
#include <hip/hip_runtime.h>
#include <hip/hip_fp16.h>
#include <math.h>

// ---- ws layout (bytes) ----
// contribH (fp16): [0, 25,886,720) as [v<5056][w*512+c]
// feat:     [25,886,720, +8,552,448) -> ends 34,439,168
// dedup:    @34,439,168: flags[2048] (+0), nUsed (+8192), list[2048] (+8448) -> ends +16,640
// A_h  fp16 [5056][320] @34,459,648 (3,235,840) -> ends 37,695,488   (contrib GEMM, dead after)
// B_h  fp16 [2560][320] @37,695,488 (1,638,400) -> ends 39,333,888   (contrib GEMM, dead after)
// B_hp fp16 [2][512][512] @39,333,888 (1,048,576) -> ends 40,382,464 (proj GEMM)
// WhhH fp16 [2][512][128] @40,382,464 (262,144) -> ends 40,644,608   (recurrence weights)
// A_hp fp16 [4224][512] @34,459,648 (4,325,376) -> ends 38,785,024   (proj GEMM; reuses dead A_h/B_h)
// post-conv aliases (contrib dead after convs):
//   preAll @2,097,152 (-> 19,202,048),
//   hT @19,202,048  hB @21,299,200  hC @23,396,352  (each 2,097,152, fp32)
//   hD @25,493,504 (32,768, fp32)   pOut @25,526,272 (32,768, fp64)  -> ends 25,559,040
#define DEDUP_B 34439168ULL
#define AH_B    34459648ULL
#define BH_B    37695488ULL
#define BHP_B   39333888ULL
#define WHH_B   40382464ULL
#define AHP_B   34459648ULL

typedef _Float16 half8 __attribute__((ext_vector_type(8)));
typedef float f32x4 __attribute__((ext_vector_type(4)));

__device__ inline void add8(float* a, float4 r){
  const __half2* h = (const __half2*)&r;
  #pragma unroll
  for (int q = 0; q < 4; ++q){
    float2 f = __half22float2(h[q]);
    a[2*q]   += f.x;
    a[2*q+1] += f.y;
  }
}

// ---------------- fused prep: out-zero + dedup-zero + featDoc-zero + embH + wTh + wihH + whhH ----------------
__global__ __launch_bounds__(256) void k_prep(unsigned int* __restrict__ out32, int n,
                                              unsigned int* __restrict__ dd32,
                                              float* __restrict__ featDoc,
                                              const float* __restrict__ emb, _Float16* __restrict__ A_h,
                                              const float* __restrict__ convw, _Float16* __restrict__ B_h,
                                              const float* __restrict__ WihF, const float* __restrict__ WihB,
                                              _Float16* __restrict__ B_hp,
                                              const float* __restrict__ WhhF, const float* __restrict__ WhhB,
                                              _Float16* __restrict__ WhhH){
  const long o0 = n;                    // out zero
  const long o1 = o0 + 2112;            // dedup flags + nUsed (+pad)
  const long o2 = o1 + 512;             // featDoc
  const long o3 = o2 + 1617920;         // embH  (5056*320)
  const long o4 = o3 + 819200;          // wTh   (2560*320)
  const long o5 = o4 + 524288;          // wihH  (2*512*512)
  const long o6 = o5 + 131072;          // whhH  (2*512*128)
  for (long t = (long)blockIdx.x * 256 + threadIdx.x; t < o6; t += (long)gridDim.x * 256){
    if (t < o0){
      out32[t] = 0u;
    } else if (t < o1){
      dd32[t - o0] = 0u;
    } else if (t < o2){
      featDoc[t - o1] = 0.f;            // atomicMax target (relu floor 0)
    } else if (t < o3){
      long u = t - o2;
      int row = (int)(u / 320), col = (int)(u - (long)row * 320);
      float v = (row < 5053 && col < 300) ? emb[(size_t)row * 300 + col] * 1024.f : 0.f;
      A_h[u] = (_Float16)v;
    } else if (t < o4){
      long u = t - o3;
      int nn = (int)(u / 320), k = (int)(u - (long)nn * 320);
      int w = nn >> 9, c = nn & 511;
      float v = (k < 300) ? convw[((size_t)c * 300 + k) * 5 + w] : 0.f;
      B_h[u] = (_Float16)v;
    } else if (t < o5){
      long u = t - o4;
      int dir = (int)(u >> 18), r = (int)(u & 262143);
      B_hp[u] = (_Float16)((dir ? WihB : WihF)[r]);
    } else {
      long u = t - o5;
      int dir = (int)(u >> 16), r = (int)(u & 65535);
      WhhH[u] = (_Float16)((dir ? WhhB : WhhF)[r]);
    }
  }
}

// ---------------- mark used entities ----------------
__global__ __launch_bounds__(256) void k_mark(const int* __restrict__ cand, int* __restrict__ flags){
  int t = blockIdx.x * 256 + threadIdx.x;     // 2048 threads
  flags[cand[t]] = 1;
}

// ---------------- compact used entities into list ----------------
__global__ __launch_bounds__(256) void k_compact(const int* __restrict__ flags,
                                                 int* __restrict__ nUsed, int* __restrict__ list){
  int t = blockIdx.x * 256 + threadIdx.x;     // 2048 threads
  if (flags[t]){
    int s = atomicAdd(nUsed, 1);
    list[s] = t;
  }
}

// ---------------- contrib GEMM via fp16 MFMA: C[5056][2560] = A_h * B_h^T ----------------
// block = 4 waves (2x2); block tile 64x128; wave tile 32x64 = 2x4 frags 16x16; K = 10x32
__global__ __launch_bounds__(256) void k_contrib(const _Float16* __restrict__ A_h,
                                                 const _Float16* __restrict__ B_h,
                                                 __half* __restrict__ contrib){
  int tid = threadIdx.x;
  int lane = tid & 63, wid = tid >> 6;
  int wr = wid >> 1, wc = wid & 1;
  int m0 = blockIdx.x * 64 + wr * 32;          // 79 tiles -> rows < 5056
  int n0 = blockIdx.y * 128 + wc * 64;         // 20 tiles -> cols < 2560
  int lr = lane & 15, lk = (lane >> 4) * 8;

  const _Float16* Ap = A_h + (size_t)(m0 + lr) * 320 + lk;      // + fr*16*320 + kk
  const _Float16* Bp = B_h + (size_t)(n0 + lr) * 320 + lk;      // + fc*16*320 + kk

  f32x4 acc[2][4];
  #pragma unroll
  for (int fr = 0; fr < 2; ++fr)
    #pragma unroll
    for (int fc = 0; fc < 4; ++fc) acc[fr][fc] = (f32x4){0.f, 0.f, 0.f, 0.f};

  for (int kk = 0; kk < 320; kk += 32){
    half8 a0 = *(const half8*)(Ap + kk);
    half8 a1 = *(const half8*)(Ap + 16 * 320 + kk);
    half8 b0 = *(const half8*)(Bp + kk);
    half8 b1 = *(const half8*)(Bp + 16 * 320 + kk);
    half8 b2 = *(const half8*)(Bp + 32 * 320 + kk);
    half8 b3 = *(const half8*)(Bp + 48 * 320 + kk);
    acc[0][0] = __builtin_amdgcn_mfma_f32_16x16x32_f16(a0, b0, acc[0][0], 0, 0, 0);
    acc[0][1] = __builtin_amdgcn_mfma_f32_16x16x32_f16(a0, b1, acc[0][1], 0, 0, 0);
    acc[0][2] = __builtin_amdgcn_mfma_f32_16x16x32_f16(a0, b2, acc[0][2], 0, 0, 0);
    acc[0][3] = __builtin_amdgcn_mfma_f32_16x16x32_f16(a0, b3, acc[0][3], 0, 0, 0);
    acc[1][0] = __builtin_amdgcn_mfma_f32_16x16x32_f16(a1, b0, acc[1][0], 0, 0, 0);
    acc[1][1] = __builtin_amdgcn_mfma_f32_16x16x32_f16(a1, b1, acc[1][1], 0, 0, 0);
    acc[1][2] = __builtin_amdgcn_mfma_f32_16x16x32_f16(a1, b2, acc[1][2], 0, 0, 0);
    acc[1][3] = __builtin_amdgcn_mfma_f32_16x16x32_f16(a1, b3, acc[1][3], 0, 0, 0);
  }
  // C/D layout: col = lane&15, row = (lane>>4)*4 + r   (measured, dtype-independent)
  const float s = 1.f / 1024.f;
  #pragma unroll
  for (int fr = 0; fr < 2; ++fr){
    int row = m0 + fr * 16 + (lane >> 4) * 4;
    #pragma unroll
    for (int fc = 0; fc < 4; ++fc){
      int col = n0 + fc * 16 + lr;
      #pragma unroll
      for (int r = 0; r < 4; ++r)
        contrib[(size_t)(row + r) * 2560 + col] = __float2half(acc[fr][fc][r] * s);
    }
  }
}

// ---------------- char-CNN gather, merged title+body+ctx, XCD channel-split ----------------
// block ranges: [0,16384) title (L=32, list), [16384,32768) body (L=128, list),
// [32768,33280) ctx (L=128, direct). Segment bases are multiples of 8 -> g = b&7
// keeps the per-XCD 64-channel strip mapping (3.2 MB < 4 MB L2) intact.
__global__ __launch_bounds__(256) void k_conv(const int* __restrict__ title_v,
                                              const int* __restrict__ body_v,
                                              const int* __restrict__ ctx_v,
                                              const __half* __restrict__ contrib,
                                              const float* __restrict__ convb,
                                              float* __restrict__ featAll,
                                              const int* __restrict__ list,
                                              const int* __restrict__ nUsed){
  __shared__ int tok[128];
  __shared__ float red[256 * 9];      // padded stride 9 -> no bank conflict
  int bg = blockIdx.x, tid = threadIdx.x;
  const int* idx; int L, row0; bool useList;
  if (bg < 16384){ idx = title_v; L = 32;  row0 = 0;    useList = true; }
  else if (bg < 32768){ bg -= 16384; idx = body_v; L = 128; row0 = 2048; useList = true; }
  else { bg -= 32768; idx = ctx_v; L = 128; row0 = 4096; useList = false; }
  int g = bg & 7, sIdx = bg >> 3;
  int s = sIdx;
  if (useList){
    if (sIdx >= *nUsed) return;
    s = list[sIdx];
  }
  const int* row = idx + (size_t)s * L;
  for (int i = tid; i < L; i += 256) tok[i] = row[i];
  __syncthreads();
  int c8 = tid & 7;                   // channel octet within group
  int pg = tid >> 3;                  // position group 0..31
  int cOff = g * 64 + c8 * 8;         // absolute channel base (8 channels/thread)
  float bias[8], mx[8];
  {
    float4 b0 = *(const float4*)(convb + cOff);
    float4 b1 = *(const float4*)(convb + cOff + 4);
    bias[0]=b0.x; bias[1]=b0.y; bias[2]=b0.z; bias[3]=b0.w;
    bias[4]=b1.x; bias[5]=b1.y; bias[6]=b1.z; bias[7]=b1.w;
  }
  #pragma unroll
  for (int k = 0; k < 8; ++k) mx[k] = 0.f;     // relu floor folded into init
  int P = L - 4;
  int per = (P + 31) >> 5;
  int p = pg * per, pe = min(p + per, P);
  for (; p + 1 < pe; p += 2){         // 2 positions/iter -> 10 x 16B loads in flight
    float a0[8], a1[8];
    #pragma unroll
    for (int k = 0; k < 8; ++k){ a0[k] = bias[k]; a1[k] = bias[k]; }
    #pragma unroll
    for (int w = 0; w < 5; ++w){
      float4 r0 = *(const float4*)(contrib + ((size_t)tok[p + w] * 5 + w) * 512 + cOff);
      float4 r1 = *(const float4*)(contrib + ((size_t)tok[p + 1 + w] * 5 + w) * 512 + cOff);
      add8(a0, r0);
      add8(a1, r1);
    }
    #pragma unroll
    for (int k = 0; k < 8; ++k) mx[k] = fmaxf(mx[k], fmaxf(a0[k], a1[k]));
  }
  if (p < pe){                        // odd tail
    float a0[8];
    #pragma unroll
    for (int k = 0; k < 8; ++k) a0[k] = bias[k];
    #pragma unroll
    for (int w = 0; w < 5; ++w){
      float4 r0 = *(const float4*)(contrib + ((size_t)tok[p + w] * 5 + w) * 512 + cOff);
      add8(a0, r0);
    }
    #pragma unroll
    for (int k = 0; k < 8; ++k) mx[k] = fmaxf(mx[k], a0[k]);
  }
  #pragma unroll
  for (int k = 0; k < 8; ++k) red[tid * 9 + k] = mx[k];
  __syncthreads();
  if (tid < 64){                      // thread t reduces channel g*64+t over 32 pos-groups
    int c8r = tid >> 3, kr = tid & 7;
    float o = red[c8r * 9 + kr];
    #pragma unroll
    for (int q = 1; q < 32; ++q)
      o = fmaxf(o, red[(q * 8 + c8r) * 9 + kr]);
    featAll[(size_t)(row0 + s) * 512 + g * 64 + tid] = o;
  }
}

// ---------------- doc conv (fp16 table): 32 blocks x 16 positions, atomicMax merge ----------------
__global__ __launch_bounds__(256) void k_conv_doc(const int* __restrict__ doc,
                                                  const __half* __restrict__ contrib,
                                                  const float* __restrict__ convb,
                                                  float* __restrict__ featDoc){
  __shared__ int tok[512];
  __shared__ float red[256 * 9];
  int b = blockIdx.x, tid = threadIdx.x;
  for (int i = tid; i < 512; i += 256) tok[i] = doc[i];
  __syncthreads();
  int c8 = tid & 63, pg = tid >> 6;
  float bias[8], mx[8];
  {
    float4 b0 = *(const float4*)(convb + c8 * 8);
    float4 b1 = *(const float4*)(convb + c8 * 8 + 4);
    bias[0]=b0.x; bias[1]=b0.y; bias[2]=b0.z; bias[3]=b0.w;
    bias[4]=b1.x; bias[5]=b1.y; bias[6]=b1.z; bias[7]=b1.w;
  }
  #pragma unroll
  for (int k = 0; k < 8; ++k) mx[k] = 0.f;
  int p0 = b * 16, p1 = min(p0 + 16, 508);
  int n = p1 - p0;
  int per = (n + 3) >> 2;
  int p = p0 + pg * per, pe = min(p + per, p1);
  for (; p < pe; ++p){
    float a0[8];
    #pragma unroll
    for (int k = 0; k < 8; ++k) a0[k] = bias[k];
    #pragma unroll
    for (int w = 0; w < 5; ++w){
      float4 r0 = *(const float4*)(contrib + ((size_t)tok[p + w] * 5 + w) * 512 + c8 * 8);
      add8(a0, r0);
    }
    #pragma unroll
    for (int k = 0; k < 8; ++k) mx[k] = fmaxf(mx[k], a0[k]);
  }
  #pragma unroll
  for (int k = 0; k < 8; ++k) red[tid * 9 + k] = mx[k];
  __syncthreads();
  if (tid < 64){
    #pragma unroll
    for (int k = 0; k < 8; ++k){
      float o = fmaxf(fmaxf(red[tid * 9 + k], red[(tid + 64) * 9 + k]),
                      fmaxf(red[(tid + 128) * 9 + k], red[(tid + 192) * 9 + k]));
      // values >= 0 -> IEEE order == int order
      atomicMax((int*)(featDoc + tid * 8 + k), __float_as_int(o));
    }
  }
}

// ---------------- feat -> fp16 A_hp[4224][512], scaled by 2^10 ----------------
__global__ __launch_bounds__(256) void k_featH(const float* __restrict__ feat, _Float16* __restrict__ A_hp){
  int t = blockIdx.x * 256 + threadIdx.x;      // < 4224*512 = 2,162,688
  if (t >= 4224 * 512) return;
  int row = t >> 9;
  float v = (row < 4161) ? feat[t] * 1024.f : 0.f;   // rows >= 4161 never written by convs
  A_hp[t] = (_Float16)v;
}

// ---------------- input projection via fp16 MFMA: preAll[dir] = A_hp * B_hp[dir]^T + bias ----------------
// block = 4 waves (2x2); block tile 64x128; wave tile 32x64 = 2x4 frags 16x16; K = 16x32
__global__ __launch_bounds__(256) void k_proj(const _Float16* __restrict__ A_hp,
                                              const _Float16* __restrict__ B_hp,
                                              const float* __restrict__ bihF, const float* __restrict__ bhhF,
                                              const float* __restrict__ bihB, const float* __restrict__ bhhB,
                                              float* __restrict__ preAll){
  int tid = threadIdx.x;
  int lane = tid & 63, wid = tid >> 6;
  int wr = wid >> 1, wc = wid & 1;
  int dir = blockIdx.z;
  int m0 = blockIdx.x * 64 + wr * 32;          // 66 tiles -> rows < 4224
  int n0 = blockIdx.y * 128 + wc * 64;         // 4 tiles -> cols < 512
  int lr = lane & 15, lk = (lane >> 4) * 8;

  const _Float16* Ap = A_hp + (size_t)(m0 + lr) * 512 + lk;
  const _Float16* Bp = B_hp + (size_t)dir * 262144 + (size_t)(n0 + lr) * 512 + lk;

  f32x4 acc[2][4];
  #pragma unroll
  for (int fr = 0; fr < 2; ++fr)
    #pragma unroll
    for (int fc = 0; fc < 4; ++fc) acc[fr][fc] = (f32x4){0.f, 0.f, 0.f, 0.f};

  for (int kk = 0; kk < 512; kk += 32){
    half8 a0 = *(const half8*)(Ap + kk);
    half8 a1 = *(const half8*)(Ap + 16 * 512 + kk);
    half8 b0 = *(const half8*)(Bp + kk);
    half8 b1 = *(const half8*)(Bp + 16 * 512 + kk);
    half8 b2 = *(const half8*)(Bp + 32 * 512 + kk);
    half8 b3 = *(const half8*)(Bp + 48 * 512 + kk);
    acc[0][0] = __builtin_amdgcn_mfma_f32_16x16x32_f16(a0, b0, acc[0][0], 0, 0, 0);
    acc[0][1] = __builtin_amdgcn_mfma_f32_16x16x32_f16(a0, b1, acc[0][1], 0, 0, 0);
    acc[0][2] = __builtin_amdgcn_mfma_f32_16x16x32_f16(a0, b2, acc[0][2], 0, 0, 0);
    acc[0][3] = __builtin_amdgcn_mfma_f32_16x16x32_f16(a0, b3, acc[0][3], 0, 0, 0);
    acc[1][0] = __builtin_amdgcn_mfma_f32_16x16x32_f16(a1, b0, acc[1][0], 0, 0, 0);
    acc[1][1] = __builtin_amdgcn_mfma_f32_16x16x32_f16(a1, b1, acc[1][1], 0, 0, 0);
    acc[1][2] = __builtin_amdgcn_mfma_f32_16x16x32_f16(a1, b2, acc[1][2], 0, 0, 0);
    acc[1][3] = __builtin_amdgcn_mfma_f32_16x16x32_f16(a1, b3, acc[1][3], 0, 0, 0);
  }
  const float s = 1.f / 1024.f;
  const float* bih = dir ? bihB : bihF;
  const float* bhh = dir ? bhhB : bhhF;
  float* outp = preAll + (size_t)dir * 4176 * 512;
  #pragma unroll
  for (int fr = 0; fr < 2; ++fr){
    int row = m0 + fr * 16 + (lane >> 4) * 4;
    #pragma unroll
    for (int fc = 0; fc < 4; ++fc){
      int col = n0 + fc * 16 + lr;
      float bias = bih[col] + bhh[col];
      #pragma unroll
      for (int r = 0; r < 4; ++r)
        if (row + r < 4176)
          outp[(size_t)(row + r) * 512 + col] = acc[fr][fc][r] * s + bias;
    }
  }
}

// ---------------- LSTM recurrence v8 (REVERTED from v9): proven 71.9 us, VGPR 84 ----------------
// v9 post-mortem: all-lane redundant cell update quadrupled transcendental work on the
// critical path (+11 us). v8 distributes activations across the 4-lane group (one gate
// each) and gathers with 3 shuffles -- measured best. fp16 weights, v_mov pin, 512t,
// launch_bounds(512,2), grid (193,2).
__global__ __launch_bounds__(512, 2) void k_recur(const float* __restrict__ preAll,
                                                  const _Float16* __restrict__ WhhH,
                                                  const int* __restrict__ cand,
                                                  float* __restrict__ hT, float* __restrict__ hB,
                                                  float* __restrict__ hC, float* __restrict__ hD){
  int c = blockIdx.x, dir = blockIdx.y, tid = threadIdx.x;
  int lstm = (c < 64) ? 0 : (c < 128) ? 1 : (c < 192) ? 2 : 3;
  int b = (lstm == 3) ? 0 : (c - lstm * 64);
  const float* pre = preAll + (size_t)dir * 4176 * 512;
  float* hout;
  if (lstm == 0)      hout = hT + (size_t)b * 32 * 256;
  else if (lstm == 1) hout = hB + (size_t)b * 32 * 256;
  else if (lstm == 2) hout = hC + (size_t)b * 32 * 256;
  else                hout = hD;
  hout += dir * 128;

  int cidx = tid >> 2;                 // cell 0..127
  int kc = tid & 3;                    // k-chunk == gate slot (0:i 1:f 2:g 3:o)
  int k0 = kc * 32;

  // weights: gate m, halves k0..k0+31 -> wv[m][j] holds halves k0+8j..k0+8j+7
  half8 wv[4][4];                      // 64 VGPRs packed fp16
  #pragma unroll
  for (int m = 0; m < 4; ++m){
    const _Float16* wp = WhhH + (size_t)dir * 65536 + (size_t)(m * 128 + cidx) * 128 + k0;
    #pragma unroll
    for (int j = 0; j < 4; ++j)
      wv[m][j] = *(const half8*)(wp + j * 8);
  }
  {
    float* wf = (float*)wv;            // pin the 64 packed words (defeats remat; v6-proven)
    #pragma unroll
    for (int i = 0; i < 64; ++i)
      asm volatile("v_mov_b32 %0, %1" : "=v"(wf[i]) : "v"(wf[i]));
  }

  __shared__ __align__(16) float hpad[2][4][36];   // [buf][chunk][32+4 pad] bank-staggered
  __shared__ int candL[32];
  if (tid < 288) ((float*)hpad)[tid] = 0.f;
  if (lstm < 2 && tid < 32) candL[tid] = cand[b * 32 + tid];
  __syncthreads();

  // prefetch preactivation for s=0
  float pf;
  {
    int t0 = dir ? 31 : 0;
    int rowi;
    if (lstm == 0)      rowi = candL[t0];
    else if (lstm == 1) rowi = 2048 + candL[t0];
    else if (lstm == 2) rowi = 4096 + b;
    else                rowi = 4160;
    pf = pre[(size_t)rowi * 512 + kc * 128 + cidx];
  }

  float cst = 0.f;
  for (int s = 0; s < 32; ++s){
    int t = dir ? (31 - s) : s;
    int cur = s & 1, nxt = cur ^ 1;
    // issue next step's preact load early (hides under matvec)
    float pfn = 0.f;
    if (s < 31){
      int t2 = dir ? (31 - (s + 1)) : (s + 1);
      int rowi;
      if (lstm == 0)      rowi = candL[t2];
      else if (lstm == 1) rowi = 2048 + candL[t2];
      else if (lstm == 2) rowi = 4096 + b;
      else                rowi = 4160;
      pfn = pre[(size_t)rowi * 512 + kc * 128 + cidx];
    }
    // matvec partials: 4 gate cols x 32 k; (float)w_half * h_float -> v_fma_mix
    float p0 = 0.f, p1 = 0.f, p2 = 0.f, p3 = 0.f;
    #pragma unroll
    for (int j = 0; j < 4; ++j){       // 8 k per j
      float4 ha = *(const float4*)&hpad[cur][kc][j * 8];
      float4 hb = *(const float4*)&hpad[cur][kc][j * 8 + 4];
      p0 += (float)wv[0][j][0] * ha.x + (float)wv[0][j][1] * ha.y
          + (float)wv[0][j][2] * ha.z + (float)wv[0][j][3] * ha.w
          + (float)wv[0][j][4] * hb.x + (float)wv[0][j][5] * hb.y
          + (float)wv[0][j][6] * hb.z + (float)wv[0][j][7] * hb.w;
      p1 += (float)wv[1][j][0] * ha.x + (float)wv[1][j][1] * ha.y
          + (float)wv[1][j][2] * ha.z + (float)wv[1][j][3] * ha.w
          + (float)wv[1][j][4] * hb.x + (float)wv[1][j][5] * hb.y
          + (float)wv[1][j][6] * hb.z + (float)wv[1][j][7] * hb.w;
      p2 += (float)wv[2][j][0] * ha.x + (float)wv[2][j][1] * ha.y
          + (float)wv[2][j][2] * ha.z + (float)wv[2][j][3] * ha.w
          + (float)wv[2][j][4] * hb.x + (float)wv[2][j][5] * hb.y
          + (float)wv[2][j][6] * hb.z + (float)wv[2][j][7] * hb.w;
      p3 += (float)wv[3][j][0] * ha.x + (float)wv[3][j][1] * ha.y
          + (float)wv[3][j][2] * ha.z + (float)wv[3][j][3] * ha.w
          + (float)wv[3][j][4] * hb.x + (float)wv[3][j][5] * hb.y
          + (float)wv[3][j][6] * hb.z + (float)wv[3][j][7] * hb.w;
    }
    // butterfly sum over the 4-lane group (k-chunks)
    p0 += __shfl_xor(p0, 1); p0 += __shfl_xor(p0, 2);
    p1 += __shfl_xor(p1, 1); p1 += __shfl_xor(p1, 2);
    p2 += __shfl_xor(p2, 1); p2 += __shfl_xor(p2, 2);
    p3 += __shfl_xor(p3, 1); p3 += __shfl_xor(p3, 2);
    float g = (kc == 0) ? p0 : (kc == 1) ? p1 : (kc == 2) ? p2 : p3;
    g += pf;
    // per-gate activation (lane kc handles gate kc)
    float av = (kc == 2) ? tanhf(g) : 1.f / (1.f + __expf(-g));
    float a1 = __shfl_xor(av, 1);
    float a2 = __shfl_xor(av, 2);
    float a3 = __shfl_xor(av, 3);
    if (kc == 0){
      // av=sig(i), a1=sig(f), a2=tanh(g), a3=sig(o)
      cst = a1 * cst + av * a2;
      float hf = a3 * tanhf(cst);
      hpad[nxt][cidx >> 5][cidx & 31] = hf;
      hout[(size_t)t * 256 + cidx] = hf;
    }
    pf = pfn;
    __syncthreads();
  }
}

// ---------------- BiDAF attention, one block per (mention, pass) ----------------
__global__ __launch_bounds__(256) void k_att1(const float* __restrict__ hC,
                                              const float* __restrict__ hT,
                                              const float* __restrict__ hD,
                                              const float* __restrict__ hB,
                                              const float* __restrict__ wc_g, const float* __restrict__ bc_g,
                                              const float* __restrict__ wq_g, const float* __restrict__ bq_g,
                                              const float* __restrict__ wcq_g, const float* __restrict__ bcq_g,
                                              const float* __restrict__ wz_g, const float* __restrict__ bz_g,
                                              double* __restrict__ pOut){
  int b = blockIdx.x, pass = blockIdx.y, tid = threadIdx.x;
  __shared__ float cS[32][260];     // stride 260: 16B-aligned stores, conflict-free reads
  __shared__ float qS[32][260];
  __shared__ float wS[7][256];      // wc, wq, wcq, wz0, wz1, wz2, wz3
  __shared__ double q2cS[256];
  __shared__ double cwS[32], qwS[32], qzS[32], paS[32], smaxS[32], bsmS[32];
  const float* cp = pass ? hD : (hC + (size_t)b * 8192);
  const float* qp = (pass ? hB : hT) + (size_t)b * 8192;
  for (int k = tid; k < 2048; k += 256){
    int i = k >> 6, d4 = (k & 63) * 4;
    *(float4*)&cS[i][d4] = *(const float4*)(cp + i * 256 + d4);
    *(float4*)&qS[i][d4] = *(const float4*)(qp + i * 256 + d4);
  }
  wS[0][tid] = wc_g[tid];
  wS[1][tid] = wq_g[tid];
  wS[2][tid] = wcq_g[tid];
  wS[3][tid] = wz_g[tid];
  wS[4][tid] = wz_g[256 + tid];
  wS[5][tid] = wz_g[512 + tid];
  wS[6][tid] = wz_g[768 + tid];
  __syncthreads();
  int i = tid >> 3, js = tid & 7;
  {
    double a = 0, aq = 0, az = 0;
    for (int k = 0; k < 32; ++k){
      int d = js * 32 + k;
      a  += (double)cS[i][d] * (double)wS[0][d];
      aq += (double)qS[i][d] * (double)wS[1][d];
      az += (double)qS[i][d] * (double)wS[4][d];
    }
    #pragma unroll
    for (int m = 1; m < 8; m <<= 1){
      a  += __shfl_xor(a, m);
      aq += __shfl_xor(aq, m);
      az += __shfl_xor(az, m);
    }
    if (js == 0){ cwS[i] = a; qwS[i] = aq; qzS[i] = az; }
  }
  __syncthreads();
  double bsum = (double)bc_g[0] + (double)bq_g[0] + (double)bcq_g[0];
  double sa[4] = {0,0,0,0}, ta[4] = {0,0,0,0};
  for (int d = 0; d < 256; ++d){
    double cd = (double)cS[i][d];
    double cw1 = cd * (double)wS[2][d];
    double cw2 = cd * (double)wS[5][d];
    #pragma unroll
    for (int m = 0; m < 4; ++m){
      double qv = (double)qS[js + m * 8][d];
      sa[m] += cw1 * qv;
      ta[m] += cw2 * qv;
    }
  }
  {
    double cwv = cwS[i];
    double s[4], mx = -1e300;
    #pragma unroll
    for (int m = 0; m < 4; ++m){
      s[m] = sa[m] + cwv + qwS[js + m * 8] + bsum;
      mx = fmax(mx, s[m]);
    }
    #pragma unroll
    for (int m = 1; m < 8; m <<= 1) mx = fmax(mx, __shfl_xor(mx, m));
    double esum = 0, eacc = 0;
    #pragma unroll
    for (int m = 0; m < 4; ++m){
      double e = exp(s[m] - mx);
      esum += e;
      eacc += e * (qzS[js + m * 8] + ta[m]);
    }
    #pragma unroll
    for (int m = 1; m < 8; m <<= 1){
      esum += __shfl_xor(esum, m);
      eacc += __shfl_xor(eacc, m);
    }
    if (js == 0){ paS[i] = eacc / esum; smaxS[i] = mx; }
  }
  __syncthreads();
  if (tid < 32){
    double v = smaxS[tid];
    double m2 = v;
    #pragma unroll
    for (int m = 1; m < 32; m <<= 1) m2 = fmax(m2, __shfl_xor(m2, m));
    double e = exp(v - m2), ssum = e;
    #pragma unroll
    for (int m = 1; m < 32; m <<= 1) ssum += __shfl_xor(ssum, m);
    bsmS[tid] = e / ssum;
  }
  __syncthreads();
  {
    double a = 0;
    for (int ii = 0; ii < 32; ++ii) a += bsmS[ii] * (double)cS[ii][tid];
    q2cS[tid] = a;
  }
  __syncthreads();
  {
    double t1 = 0, t4 = 0;
    for (int k = 0; k < 32; ++k){
      int d = js * 32 + k;
      double cd = (double)cS[i][d];
      t1 += cd * (double)wS[3][d];
      t4 += cd * q2cS[d] * (double)wS[6][d];
    }
    #pragma unroll
    for (int m = 1; m < 8; m <<= 1){
      t1 += __shfl_xor(t1, m);
      t4 += __shfl_xor(t4, m);
    }
    if (js == 0)
      pOut[((size_t)pass * 64 + b) * 32 + i] = t1 + paS[i] + t4 + (double)bz_g[0];
  }
}

// ---------------- combine p1/p2 -> score, softmax, scatter ----------------
__global__ __launch_bounds__(64) void k_att2(const double* __restrict__ pOut,
                                             const float* __restrict__ wp1_g, const float* __restrict__ bp1_g,
                                             const float* __restrict__ wp2_g, const float* __restrict__ bp2_g,
                                             const int* __restrict__ cand,
                                             float* __restrict__ out){
  int b = blockIdx.x, tid = threadIdx.x;
  if (tid >= 32) return;
  double p1 = pOut[(size_t)b * 32 + tid];
  double p2 = pOut[(size_t)(64 + b) * 32 + tid];
  double sc = (double)wp1_g[0] * p1 + (double)bp1_g[0]
            + (double)wp2_g[0] * p2 + (double)bp2_g[0];
  double mx = sc, rs = sc;
  #pragma unroll
  for (int m = 1; m < 32; m <<= 1){
    mx = fmax(mx, __shfl_xor(mx, m));
    rs += __shfl_xor(rs, m);
  }
  double e = exp(sc - mx), es = e;
  #pragma unroll
  for (int m = 1; m < 32; m <<= 1) es += __shfl_xor(es, m);
  int col = cand[b * 32 + tid];
  out[(size_t)b * 2048 + col] = (float)sc;
  out[131072 + (size_t)b * 2048 + col] = (float)(e / es);
  out[262144 + (size_t)b * 2048 + col] = (float)(sc / rs);
}

// ---------------------------------------------------------------------------
extern "C" void kernel_launch(void* const* d_in, const int* in_sizes, int n_in,
                              void* d_out, int out_size, void* d_ws, size_t ws_size,
                              hipStream_t stream) {
  const int* title_v = (const int*)d_in[0];
  const int* body_v  = (const int*)d_in[1];
  const int* ctx_v   = (const int*)d_in[3];
  const int* doc_v   = (const int*)d_in[4];
  const int* cand    = (const int*)d_in[5];
  const float* emb   = (const float*)d_in[6];
  const float* convw = (const float*)d_in[7];
  const float* convb = (const float*)d_in[8];
  const float* WihF  = (const float*)d_in[9];
  const float* WhhF  = (const float*)d_in[10];
  const float* bihF  = (const float*)d_in[11];
  const float* bhhF  = (const float*)d_in[12];
  const float* WihB  = (const float*)d_in[13];
  const float* WhhB  = (const float*)d_in[14];
  const float* bihB  = (const float*)d_in[15];
  const float* bhhB  = (const float*)d_in[16];
  float* out = (float*)d_out;

  const size_t CONTRIB_B = (size_t)5056 * 2560 * 2;     // 25,886,720 (fp16)
  char* base = (char*)d_ws;
  if (ws_size < 60325888) return;
  __half* contrib = (__half*)base;
  char* featBase = base + CONTRIB_B;                    // 25,886,720
  float* feat = (float*)featBase;
  float* featDoc = feat + (size_t)4160 * 512;

  // dedup buffers after feat (dead once convs complete)
  int* flags = (int*)(base + DEDUP_B);
  int* nUsed = (int*)(base + DEDUP_B + 8192);
  int* list  = (int*)(base + DEDUP_B + 8448);

  // fp16 GEMM / recurrence inputs
  _Float16* A_h  = (_Float16*)(base + AH_B);            // contrib GEMM A (dead after k_contrib)
  _Float16* B_h  = (_Float16*)(base + BH_B);            // contrib GEMM B (dead after k_contrib)
  _Float16* A_hp = (_Float16*)(base + AHP_B);           // proj GEMM A (reuses A_h/B_h space)
  _Float16* B_hp = (_Float16*)(base + BHP_B);           // proj GEMM B
  _Float16* WhhH = (_Float16*)(base + WHH_B);           // recurrence weights fp16

  // post-conv aliases (contrib dead after convs; feat/dedup dead after k_featH/k_proj)
  float*  preAll = (float*)(base + 2097152);            // -> 19,202,048
  float*  hT     = (float*)(base + 19202048);           // 2,097,152 each (fp32)
  float*  hB     = (float*)(base + 21299200);
  float*  hC     = (float*)(base + 23396352);
  float*  hD     = (float*)(base + 25493504);           // 32,768
  double* pOut   = (double*)(base + 25526272);          // 32,768 -> ends 25,559,040

  k_prep<<<4096, 256, 0, stream>>>((unsigned int*)out, out_size,
                                   (unsigned int*)(base + DEDUP_B), featDoc,
                                   emb, A_h, convw, B_h, WihF, WihB, B_hp,
                                   WhhF, WhhB, WhhH);
  k_mark<<<8, 256, 0, stream>>>(cand, flags);
  k_compact<<<8, 256, 0, stream>>>(flags, nUsed, list);
  k_contrib<<<dim3(79, 20), 256, 0, stream>>>(A_h, B_h, contrib);

  k_conv<<<33280, 256, 0, stream>>>(title_v, body_v, ctx_v, contrib, convb, feat, list, nUsed);
  k_conv_doc<<<32, 256, 0, stream>>>(doc_v, contrib, convb, featDoc);

  k_featH<<<8448, 256, 0, stream>>>(feat, A_hp);
  k_proj<<<dim3(66, 4, 2), 256, 0, stream>>>(A_hp, B_hp, bihF, bhhF, bihB, bhhB, preAll);
  k_recur<<<dim3(193, 2), 512, 0, stream>>>(preAll, WhhH, cand, hT, hB, hC, hD);
  k_att1<<<dim3(64, 2), 256, 0, stream>>>(hC, hT, hD, hB,
                                (const float*)d_in[17], (const float*)d_in[18],
                                (const float*)d_in[19], (const float*)d_in[20],
                                (const float*)d_in[21], (const float*)d_in[22],
                                (const float*)d_in[23], (const float*)d_in[24],
                                pOut);
  k_att2<<<64, 64, 0, stream>>>(pOut,
                                (const float*)d_in[25], (const float*)d_in[26],
                                (const float*)d_in[27], (const float*)d_in[28],
                                cand, out);
}

// Round 16
// 354.041 us; speedup vs baseline: 1.0703x; 1.0377x over previous
//
#include <hip/hip_runtime.h>
#include <hip/hip_fp16.h>
#include <math.h>

// ---- ws layout (bytes) ----
// contribH (fp16): [0, 25,886,720) as [v<5056][w*512+c]
// featDoc fp32[512] @ 25,886,720 + 4160*512*4 = 34,406,400 (row 4160 slot of old feat region)
// dedup:    @34,439,168: nUsed (+0), list[2048] (+256)
// A_h  fp16 [5056][320] @34,459,648 (3,235,840)   (contrib GEMM A, dead after k_contrib)
// B_h  fp16 [2560][320] @37,695,488 (1,638,400)   (contrib GEMM B, dead after k_contrib)
// B_hp fp16 [2][512][512] @39,333,888 (1,048,576) (proj GEMM B)
// WhhH fp16 [2][512][128] @40,382,464 (262,144)   (recurrence weights)
// A_hp fp16 [4224][512] @34,459,648 (4,325,376)   (proj GEMM A; written by conv epilogue,
//                                                  reuses dead A_h/B_h space)
// post-conv aliases (contrib dead after convs):
//   preAll @2,097,152 (-> 19,202,048),
//   hT @19,202,048  hB @21,299,200  hC @23,396,352  (each 2,097,152, fp32)
//   hD @25,493,504 (32,768, fp32)   pOut @25,526,272 (32,768, fp64)
#define DEDUP_B 34439168ULL
#define AH_B    34459648ULL
#define BH_B    37695488ULL
#define BHP_B   39333888ULL
#define WHH_B   40382464ULL
#define AHP_B   34459648ULL

typedef _Float16 half8 __attribute__((ext_vector_type(8)));
typedef float f32x4 __attribute__((ext_vector_type(4)));

__device__ inline void add8(float* a, float4 r){
  const __half2* h = (const __half2*)&r;
  #pragma unroll
  for (int q = 0; q < 4; ++q){
    float2 f = __half22float2(h[q]);
    a[2*q]   += f.x;
    a[2*q+1] += f.y;
  }
}

// ---------------- fused prep: out-zero + featDoc-zero + embH + wTh + wihH + whhH ----------------
__global__ __launch_bounds__(256) void k_prep(unsigned int* __restrict__ out32, int n,
                                              float* __restrict__ featDoc,
                                              const float* __restrict__ emb, _Float16* __restrict__ A_h,
                                              const float* __restrict__ convw, _Float16* __restrict__ B_h,
                                              const float* __restrict__ WihF, const float* __restrict__ WihB,
                                              _Float16* __restrict__ B_hp,
                                              const float* __restrict__ WhhF, const float* __restrict__ WhhB,
                                              _Float16* __restrict__ WhhH){
  const long o0 = n;                    // out zero
  const long o1 = o0 + 512;             // featDoc
  const long o2 = o1 + 1617920;         // embH  (5056*320)
  const long o3 = o2 + 819200;          // wTh   (2560*320)
  const long o4 = o3 + 524288;          // wihH  (2*512*512)
  const long o5 = o4 + 131072;          // whhH  (2*512*128)
  for (long t = (long)blockIdx.x * 256 + threadIdx.x; t < o5; t += (long)gridDim.x * 256){
    if (t < o0){
      out32[t] = 0u;
    } else if (t < o1){
      featDoc[t - o0] = 0.f;            // atomicMax target (relu floor 0)
    } else if (t < o2){
      long u = t - o1;
      int row = (int)(u / 320), col = (int)(u - (long)row * 320);
      float v = (row < 5053 && col < 300) ? emb[(size_t)row * 300 + col] * 1024.f : 0.f;
      A_h[u] = (_Float16)v;
    } else if (t < o3){
      long u = t - o2;
      int nn = (int)(u / 320), k = (int)(u - (long)nn * 320);
      int w = nn >> 9, c = nn & 511;
      float v = (k < 300) ? convw[((size_t)c * 300 + k) * 5 + w] : 0.f;
      B_h[u] = (_Float16)v;
    } else if (t < o4){
      long u = t - o3;
      int dir = (int)(u >> 18), r = (int)(u & 262143);
      B_hp[u] = (_Float16)((dir ? WihB : WihF)[r]);
    } else {
      long u = t - o4;
      int dir = (int)(u >> 16), r = (int)(u & 65535);
      WhhH[u] = (_Float16)((dir ? WhhB : WhhF)[r]);
    }
  }
}

// ---------------- fused mark+compact: ONE block, LDS flags ----------------
__global__ __launch_bounds__(1024) void k_markcompact(const int* __restrict__ cand,
                                                      int* __restrict__ nUsed,
                                                      int* __restrict__ list){
  __shared__ int flags[2048];
  __shared__ int cnt;
  int tid = threadIdx.x;
  flags[tid] = 0; flags[tid + 1024] = 0;
  if (tid == 0) cnt = 0;
  __syncthreads();
  flags[cand[tid]] = 1;
  flags[cand[tid + 1024]] = 1;
  __syncthreads();
  #pragma unroll
  for (int q = 0; q < 2; ++q){
    int e = tid + q * 1024;
    if (flags[e]){
      int s = atomicAdd(&cnt, 1);
      list[s] = e;
    }
  }
  __syncthreads();
  if (tid == 0) *nUsed = cnt;
}

// ---------------- contrib GEMM via fp16 MFMA: C[5056][2560] = A_h * B_h^T ----------------
// block = 4 waves (2x2); block tile 64x128; wave tile 32x64 = 2x4 frags 16x16; K = 10x32
__global__ __launch_bounds__(256) void k_contrib(const _Float16* __restrict__ A_h,
                                                 const _Float16* __restrict__ B_h,
                                                 __half* __restrict__ contrib){
  int tid = threadIdx.x;
  int lane = tid & 63, wid = tid >> 6;
  int wr = wid >> 1, wc = wid & 1;
  int m0 = blockIdx.x * 64 + wr * 32;          // 79 tiles -> rows < 5056
  int n0 = blockIdx.y * 128 + wc * 64;         // 20 tiles -> cols < 2560
  int lr = lane & 15, lk = (lane >> 4) * 8;

  const _Float16* Ap = A_h + (size_t)(m0 + lr) * 320 + lk;      // + fr*16*320 + kk
  const _Float16* Bp = B_h + (size_t)(n0 + lr) * 320 + lk;      // + fc*16*320 + kk

  f32x4 acc[2][4];
  #pragma unroll
  for (int fr = 0; fr < 2; ++fr)
    #pragma unroll
    for (int fc = 0; fc < 4; ++fc) acc[fr][fc] = (f32x4){0.f, 0.f, 0.f, 0.f};

  for (int kk = 0; kk < 320; kk += 32){
    half8 a0 = *(const half8*)(Ap + kk);
    half8 a1 = *(const half8*)(Ap + 16 * 320 + kk);
    half8 b0 = *(const half8*)(Bp + kk);
    half8 b1 = *(const half8*)(Bp + 16 * 320 + kk);
    half8 b2 = *(const half8*)(Bp + 32 * 320 + kk);
    half8 b3 = *(const half8*)(Bp + 48 * 320 + kk);
    acc[0][0] = __builtin_amdgcn_mfma_f32_16x16x32_f16(a0, b0, acc[0][0], 0, 0, 0);
    acc[0][1] = __builtin_amdgcn_mfma_f32_16x16x32_f16(a0, b1, acc[0][1], 0, 0, 0);
    acc[0][2] = __builtin_amdgcn_mfma_f32_16x16x32_f16(a0, b2, acc[0][2], 0, 0, 0);
    acc[0][3] = __builtin_amdgcn_mfma_f32_16x16x32_f16(a0, b3, acc[0][3], 0, 0, 0);
    acc[1][0] = __builtin_amdgcn_mfma_f32_16x16x32_f16(a1, b0, acc[1][0], 0, 0, 0);
    acc[1][1] = __builtin_amdgcn_mfma_f32_16x16x32_f16(a1, b1, acc[1][1], 0, 0, 0);
    acc[1][2] = __builtin_amdgcn_mfma_f32_16x16x32_f16(a1, b2, acc[1][2], 0, 0, 0);
    acc[1][3] = __builtin_amdgcn_mfma_f32_16x16x32_f16(a1, b3, acc[1][3], 0, 0, 0);
  }
  // C/D layout: col = lane&15, row = (lane>>4)*4 + r   (measured, dtype-independent)
  const float s = 1.f / 1024.f;
  #pragma unroll
  for (int fr = 0; fr < 2; ++fr){
    int row = m0 + fr * 16 + (lane >> 4) * 4;
    #pragma unroll
    for (int fc = 0; fc < 4; ++fc){
      int col = n0 + fc * 16 + lr;
      #pragma unroll
      for (int r = 0; r < 4; ++r)
        contrib[(size_t)(row + r) * 2560 + col] = __float2half(acc[fr][fc][r] * s);
    }
  }
}

// ---------------- merged char-CNN: title+body+ctx (XCD channel-split) + doc ----------------
// block ranges: [0,16384) title (L=32, list), [16384,32768) body (L=128, list),
// [32768,33280) ctx (L=128, direct), [33280,33312) doc (atomicMax featDoc).
// Segment bases are multiples of 8 -> g = b&7 keeps the per-XCD 64-channel strip
// mapping (3.2 MB < 4 MB L2) intact. Conv epilogue writes fp16 A_hp DIRECTLY
// (half(o*1024) == old fp32-store->reload->x1024->fp16 path bit-exactly).
__global__ __launch_bounds__(256) void k_conv(const int* __restrict__ title_v,
                                              const int* __restrict__ body_v,
                                              const int* __restrict__ ctx_v,
                                              const int* __restrict__ doc_v,
                                              const __half* __restrict__ contrib,
                                              const float* __restrict__ convb,
                                              _Float16* __restrict__ A_hp,
                                              float* __restrict__ featDoc,
                                              const int* __restrict__ list,
                                              const int* __restrict__ nUsed){
  __shared__ int tok[512];
  __shared__ float red[256 * 9];      // padded stride 9 -> no bank conflict
  int bg = blockIdx.x, tid = threadIdx.x;

  if (bg >= 33280){                   // ---- doc path ----
    int b = bg - 33280;
    for (int i = tid; i < 512; i += 256) tok[i] = doc_v[i];
    __syncthreads();
    int c8 = tid & 63, pg = tid >> 6;
    float bias[8], mx[8];
    {
      float4 b0 = *(const float4*)(convb + c8 * 8);
      float4 b1 = *(const float4*)(convb + c8 * 8 + 4);
      bias[0]=b0.x; bias[1]=b0.y; bias[2]=b0.z; bias[3]=b0.w;
      bias[4]=b1.x; bias[5]=b1.y; bias[6]=b1.z; bias[7]=b1.w;
    }
    #pragma unroll
    for (int k = 0; k < 8; ++k) mx[k] = 0.f;
    int p0 = b * 16, p1 = min(p0 + 16, 508);
    int n = p1 - p0;
    int per = (n + 3) >> 2;
    int p = p0 + pg * per, pe = min(p + per, p1);
    for (; p < pe; ++p){
      float a0[8];
      #pragma unroll
      for (int k = 0; k < 8; ++k) a0[k] = bias[k];
      #pragma unroll
      for (int w = 0; w < 5; ++w){
        float4 r0 = *(const float4*)(contrib + ((size_t)tok[p + w] * 5 + w) * 512 + c8 * 8);
        add8(a0, r0);
      }
      #pragma unroll
      for (int k = 0; k < 8; ++k) mx[k] = fmaxf(mx[k], a0[k]);
    }
    #pragma unroll
    for (int k = 0; k < 8; ++k) red[tid * 9 + k] = mx[k];
    __syncthreads();
    if (tid < 64){
      #pragma unroll
      for (int k = 0; k < 8; ++k){
        float o = fmaxf(fmaxf(red[tid * 9 + k], red[(tid + 64) * 9 + k]),
                        fmaxf(red[(tid + 128) * 9 + k], red[(tid + 192) * 9 + k]));
        // values >= 0 -> IEEE order == int order
        atomicMax((int*)(featDoc + tid * 8 + k), __float_as_int(o));
      }
    }
    return;
  }

  // ---- title/body/ctx path ----
  const int* idx; int L, row0; bool useList;
  if (bg < 16384){ idx = title_v; L = 32;  row0 = 0;    useList = true; }
  else if (bg < 32768){ bg -= 16384; idx = body_v; L = 128; row0 = 2048; useList = true; }
  else { bg -= 32768; idx = ctx_v; L = 128; row0 = 4096; useList = false; }
  int g = bg & 7, sIdx = bg >> 3;
  int s = sIdx;
  if (useList){
    if (sIdx >= *nUsed) return;
    s = list[sIdx];
  }
  const int* row = idx + (size_t)s * L;
  for (int i = tid; i < L; i += 256) tok[i] = row[i];
  __syncthreads();
  int c8 = tid & 7;                   // channel octet within group
  int pg = tid >> 3;                  // position group 0..31
  int cOff = g * 64 + c8 * 8;         // absolute channel base (8 channels/thread)
  float bias[8], mx[8];
  {
    float4 b0 = *(const float4*)(convb + cOff);
    float4 b1 = *(const float4*)(convb + cOff + 4);
    bias[0]=b0.x; bias[1]=b0.y; bias[2]=b0.z; bias[3]=b0.w;
    bias[4]=b1.x; bias[5]=b1.y; bias[6]=b1.z; bias[7]=b1.w;
  }
  #pragma unroll
  for (int k = 0; k < 8; ++k) mx[k] = 0.f;     // relu floor folded into init
  int P = L - 4;
  int per = (P + 31) >> 5;
  int p = pg * per, pe = min(p + per, P);
  for (; p + 1 < pe; p += 2){         // 2 positions/iter -> 10 x 16B loads in flight
    float a0[8], a1[8];
    #pragma unroll
    for (int k = 0; k < 8; ++k){ a0[k] = bias[k]; a1[k] = bias[k]; }
    #pragma unroll
    for (int w = 0; w < 5; ++w){
      float4 r0 = *(const float4*)(contrib + ((size_t)tok[p + w] * 5 + w) * 512 + cOff);
      float4 r1 = *(const float4*)(contrib + ((size_t)tok[p + 1 + w] * 5 + w) * 512 + cOff);
      add8(a0, r0);
      add8(a1, r1);
    }
    #pragma unroll
    for (int k = 0; k < 8; ++k) mx[k] = fmaxf(mx[k], fmaxf(a0[k], a1[k]));
  }
  if (p < pe){                        // odd tail
    float a0[8];
    #pragma unroll
    for (int k = 0; k < 8; ++k) a0[k] = bias[k];
    #pragma unroll
    for (int w = 0; w < 5; ++w){
      float4 r0 = *(const float4*)(contrib + ((size_t)tok[p + w] * 5 + w) * 512 + cOff);
      add8(a0, r0);
    }
    #pragma unroll
    for (int k = 0; k < 8; ++k) mx[k] = fmaxf(mx[k], a0[k]);
  }
  #pragma unroll
  for (int k = 0; k < 8; ++k) red[tid * 9 + k] = mx[k];
  __syncthreads();
  if (tid < 64){                      // thread t reduces channel g*64+t over 32 pos-groups
    int c8r = tid >> 3, kr = tid & 7;
    float o = red[c8r * 9 + kr];
    #pragma unroll
    for (int q = 1; q < 32; ++q)
      o = fmaxf(o, red[(q * 8 + c8r) * 9 + kr]);
    A_hp[(size_t)(row0 + s) * 512 + g * 64 + tid] = (_Float16)(o * 1024.f);
  }
}

// ---------------- featTail: A_hp doc row (4160) from featDoc + zero pad rows 4161.. ----------------
// 128 blocks x 256 threads cover 512 + 63*512 = 32768 elements exactly
__global__ __launch_bounds__(256) void k_featTail(const float* __restrict__ featDoc,
                                                  _Float16* __restrict__ A_hp){
  int t = blockIdx.x * 256 + threadIdx.x;
  if (t < 512)
    A_hp[(size_t)4160 * 512 + t] = (_Float16)(featDoc[t] * 1024.f);
  else
    A_hp[(size_t)4160 * 512 + t] = (_Float16)0.f;   // rows 4161..4223 pad
}

// ---------------- input projection via fp16 MFMA: preAll[dir] = A_hp * B_hp[dir]^T + bias ----------------
// block = 4 waves (2x2); block tile 64x128; wave tile 32x64 = 2x4 frags 16x16; K = 16x32
__global__ __launch_bounds__(256) void k_proj(const _Float16* __restrict__ A_hp,
                                              const _Float16* __restrict__ B_hp,
                                              const float* __restrict__ bihF, const float* __restrict__ bhhF,
                                              const float* __restrict__ bihB, const float* __restrict__ bhhB,
                                              float* __restrict__ preAll){
  int tid = threadIdx.x;
  int lane = tid & 63, wid = tid >> 6;
  int wr = wid >> 1, wc = wid & 1;
  int dir = blockIdx.z;
  int m0 = blockIdx.x * 64 + wr * 32;          // 66 tiles -> rows < 4224
  int n0 = blockIdx.y * 128 + wc * 64;         // 4 tiles -> cols < 512
  int lr = lane & 15, lk = (lane >> 4) * 8;

  const _Float16* Ap = A_hp + (size_t)(m0 + lr) * 512 + lk;
  const _Float16* Bp = B_hp + (size_t)dir * 262144 + (size_t)(n0 + lr) * 512 + lk;

  f32x4 acc[2][4];
  #pragma unroll
  for (int fr = 0; fr < 2; ++fr)
    #pragma unroll
    for (int fc = 0; fc < 4; ++fc) acc[fr][fc] = (f32x4){0.f, 0.f, 0.f, 0.f};

  for (int kk = 0; kk < 512; kk += 32){
    half8 a0 = *(const half8*)(Ap + kk);
    half8 a1 = *(const half8*)(Ap + 16 * 512 + kk);
    half8 b0 = *(const half8*)(Bp + kk);
    half8 b1 = *(const half8*)(Bp + 16 * 512 + kk);
    half8 b2 = *(const half8*)(Bp + 32 * 512 + kk);
    half8 b3 = *(const half8*)(Bp + 48 * 512 + kk);
    acc[0][0] = __builtin_amdgcn_mfma_f32_16x16x32_f16(a0, b0, acc[0][0], 0, 0, 0);
    acc[0][1] = __builtin_amdgcn_mfma_f32_16x16x32_f16(a0, b1, acc[0][1], 0, 0, 0);
    acc[0][2] = __builtin_amdgcn_mfma_f32_16x16x32_f16(a0, b2, acc[0][2], 0, 0, 0);
    acc[0][3] = __builtin_amdgcn_mfma_f32_16x16x32_f16(a0, b3, acc[0][3], 0, 0, 0);
    acc[1][0] = __builtin_amdgcn_mfma_f32_16x16x32_f16(a1, b0, acc[1][0], 0, 0, 0);
    acc[1][1] = __builtin_amdgcn_mfma_f32_16x16x32_f16(a1, b1, acc[1][1], 0, 0, 0);
    acc[1][2] = __builtin_amdgcn_mfma_f32_16x16x32_f16(a1, b2, acc[1][2], 0, 0, 0);
    acc[1][3] = __builtin_amdgcn_mfma_f32_16x16x32_f16(a1, b3, acc[1][3], 0, 0, 0);
  }
  const float s = 1.f / 1024.f;
  const float* bih = dir ? bihB : bihF;
  const float* bhh = dir ? bhhB : bhhF;
  float* outp = preAll + (size_t)dir * 4176 * 512;
  #pragma unroll
  for (int fr = 0; fr < 2; ++fr){
    int row = m0 + fr * 16 + (lane >> 4) * 4;
    #pragma unroll
    for (int fc = 0; fc < 4; ++fc){
      int col = n0 + fc * 16 + lr;
      float bias = bih[col] + bhh[col];
      #pragma unroll
      for (int r = 0; r < 4; ++r)
        if (row + r < 4176)
          outp[(size_t)(row + r) * 512 + col] = acc[fr][fc][r] * s + bias;
    }
  }
}

// ---------------- LSTM recurrence v8 (proven 71.9 us, VGPR 84) ----------------
__global__ __launch_bounds__(512, 2) void k_recur(const float* __restrict__ preAll,
                                                  const _Float16* __restrict__ WhhH,
                                                  const int* __restrict__ cand,
                                                  float* __restrict__ hT, float* __restrict__ hB,
                                                  float* __restrict__ hC, float* __restrict__ hD){
  int c = blockIdx.x, dir = blockIdx.y, tid = threadIdx.x;
  int lstm = (c < 64) ? 0 : (c < 128) ? 1 : (c < 192) ? 2 : 3;
  int b = (lstm == 3) ? 0 : (c - lstm * 64);
  const float* pre = preAll + (size_t)dir * 4176 * 512;
  float* hout;
  if (lstm == 0)      hout = hT + (size_t)b * 32 * 256;
  else if (lstm == 1) hout = hB + (size_t)b * 32 * 256;
  else if (lstm == 2) hout = hC + (size_t)b * 32 * 256;
  else                hout = hD;
  hout += dir * 128;

  int cidx = tid >> 2;                 // cell 0..127
  int kc = tid & 3;                    // k-chunk == gate slot (0:i 1:f 2:g 3:o)
  int k0 = kc * 32;

  // weights: gate m, halves k0..k0+31 -> wv[m][j] holds halves k0+8j..k0+8j+7
  half8 wv[4][4];                      // 64 VGPRs packed fp16
  #pragma unroll
  for (int m = 0; m < 4; ++m){
    const _Float16* wp = WhhH + (size_t)dir * 65536 + (size_t)(m * 128 + cidx) * 128 + k0;
    #pragma unroll
    for (int j = 0; j < 4; ++j)
      wv[m][j] = *(const half8*)(wp + j * 8);
  }
  {
    float* wf = (float*)wv;            // pin the 64 packed words (defeats remat; v6-proven)
    #pragma unroll
    for (int i = 0; i < 64; ++i)
      asm volatile("v_mov_b32 %0, %1" : "=v"(wf[i]) : "v"(wf[i]));
  }

  __shared__ __align__(16) float hpad[2][4][36];   // [buf][chunk][32+4 pad] bank-staggered
  __shared__ int candL[32];
  if (tid < 288) ((float*)hpad)[tid] = 0.f;
  if (lstm < 2 && tid < 32) candL[tid] = cand[b * 32 + tid];
  __syncthreads();

  // prefetch preactivation for s=0
  float pf;
  {
    int t0 = dir ? 31 : 0;
    int rowi;
    if (lstm == 0)      rowi = candL[t0];
    else if (lstm == 1) rowi = 2048 + candL[t0];
    else if (lstm == 2) rowi = 4096 + b;
    else                rowi = 4160;
    pf = pre[(size_t)rowi * 512 + kc * 128 + cidx];
  }

  float cst = 0.f;
  for (int s = 0; s < 32; ++s){
    int t = dir ? (31 - s) : s;
    int cur = s & 1, nxt = cur ^ 1;
    // issue next step's preact load early (hides under matvec)
    float pfn = 0.f;
    if (s < 31){
      int t2 = dir ? (31 - (s + 1)) : (s + 1);
      int rowi;
      if (lstm == 0)      rowi = candL[t2];
      else if (lstm == 1) rowi = 2048 + candL[t2];
      else if (lstm == 2) rowi = 4096 + b;
      else                rowi = 4160;
      pfn = pre[(size_t)rowi * 512 + kc * 128 + cidx];
    }
    // matvec partials: 4 gate cols x 32 k; (float)w_half * h_float -> v_fma_mix
    float p0 = 0.f, p1 = 0.f, p2 = 0.f, p3 = 0.f;
    #pragma unroll
    for (int j = 0; j < 4; ++j){       // 8 k per j
      float4 ha = *(const float4*)&hpad[cur][kc][j * 8];
      float4 hb = *(const float4*)&hpad[cur][kc][j * 8 + 4];
      p0 += (float)wv[0][j][0] * ha.x + (float)wv[0][j][1] * ha.y
          + (float)wv[0][j][2] * ha.z + (float)wv[0][j][3] * ha.w
          + (float)wv[0][j][4] * hb.x + (float)wv[0][j][5] * hb.y
          + (float)wv[0][j][6] * hb.z + (float)wv[0][j][7] * hb.w;
      p1 += (float)wv[1][j][0] * ha.x + (float)wv[1][j][1] * ha.y
          + (float)wv[1][j][2] * ha.z + (float)wv[1][j][3] * ha.w
          + (float)wv[1][j][4] * hb.x + (float)wv[1][j][5] * hb.y
          + (float)wv[1][j][6] * hb.z + (float)wv[1][j][7] * hb.w;
      p2 += (float)wv[2][j][0] * ha.x + (float)wv[2][j][1] * ha.y
          + (float)wv[2][j][2] * ha.z + (float)wv[2][j][3] * ha.w
          + (float)wv[2][j][4] * hb.x + (float)wv[2][j][5] * hb.y
          + (float)wv[2][j][6] * hb.z + (float)wv[2][j][7] * hb.w;
      p3 += (float)wv[3][j][0] * ha.x + (float)wv[3][j][1] * ha.y
          + (float)wv[3][j][2] * ha.z + (float)wv[3][j][3] * ha.w
          + (float)wv[3][j][4] * hb.x + (float)wv[3][j][5] * hb.y
          + (float)wv[3][j][6] * hb.z + (float)wv[3][j][7] * hb.w;
    }
    // butterfly sum over the 4-lane group (k-chunks)
    p0 += __shfl_xor(p0, 1); p0 += __shfl_xor(p0, 2);
    p1 += __shfl_xor(p1, 1); p1 += __shfl_xor(p1, 2);
    p2 += __shfl_xor(p2, 1); p2 += __shfl_xor(p2, 2);
    p3 += __shfl_xor(p3, 1); p3 += __shfl_xor(p3, 2);
    float g = (kc == 0) ? p0 : (kc == 1) ? p1 : (kc == 2) ? p2 : p3;
    g += pf;
    // per-gate activation (lane kc handles gate kc)
    float av = (kc == 2) ? tanhf(g) : 1.f / (1.f + __expf(-g));
    float a1 = __shfl_xor(av, 1);
    float a2 = __shfl_xor(av, 2);
    float a3 = __shfl_xor(av, 3);
    if (kc == 0){
      // av=sig(i), a1=sig(f), a2=tanh(g), a3=sig(o)
      cst = a1 * cst + av * a2;
      float hf = a3 * tanhf(cst);
      hpad[nxt][cidx >> 5][cidx & 31] = hf;
      hout[(size_t)t * 256 + cidx] = hf;
    }
    pf = pfn;
    __syncthreads();
  }
}

// ---------------- BiDAF attention, one block per (mention, pass) ----------------
__global__ __launch_bounds__(256) void k_att1(const float* __restrict__ hC,
                                              const float* __restrict__ hT,
                                              const float* __restrict__ hD,
                                              const float* __restrict__ hB,
                                              const float* __restrict__ wc_g, const float* __restrict__ bc_g,
                                              const float* __restrict__ wq_g, const float* __restrict__ bq_g,
                                              const float* __restrict__ wcq_g, const float* __restrict__ bcq_g,
                                              const float* __restrict__ wz_g, const float* __restrict__ bz_g,
                                              double* __restrict__ pOut){
  int b = blockIdx.x, pass = blockIdx.y, tid = threadIdx.x;
  __shared__ float cS[32][260];     // stride 260: 16B-aligned stores, conflict-free reads
  __shared__ float qS[32][260];
  __shared__ float wS[7][256];      // wc, wq, wcq, wz0, wz1, wz2, wz3
  __shared__ double q2cS[256];
  __shared__ double cwS[32], qwS[32], qzS[32], paS[32], smaxS[32], bsmS[32];
  const float* cp = pass ? hD : (hC + (size_t)b * 8192);
  const float* qp = (pass ? hB : hT) + (size_t)b * 8192;
  for (int k = tid; k < 2048; k += 256){
    int i = k >> 6, d4 = (k & 63) * 4;
    *(float4*)&cS[i][d4] = *(const float4*)(cp + i * 256 + d4);
    *(float4*)&qS[i][d4] = *(const float4*)(qp + i * 256 + d4);
  }
  wS[0][tid] = wc_g[tid];
  wS[1][tid] = wq_g[tid];
  wS[2][tid] = wcq_g[tid];
  wS[3][tid] = wz_g[tid];
  wS[4][tid] = wz_g[256 + tid];
  wS[5][tid] = wz_g[512 + tid];
  wS[6][tid] = wz_g[768 + tid];
  __syncthreads();
  int i = tid >> 3, js = tid & 7;
  {
    double a = 0, aq = 0, az = 0;
    for (int k = 0; k < 32; ++k){
      int d = js * 32 + k;
      a  += (double)cS[i][d] * (double)wS[0][d];
      aq += (double)qS[i][d] * (double)wS[1][d];
      az += (double)qS[i][d] * (double)wS[4][d];
    }
    #pragma unroll
    for (int m = 1; m < 8; m <<= 1){
      a  += __shfl_xor(a, m);
      aq += __shfl_xor(aq, m);
      az += __shfl_xor(az, m);
    }
    if (js == 0){ cwS[i] = a; qwS[i] = aq; qzS[i] = az; }
  }
  __syncthreads();
  double bsum = (double)bc_g[0] + (double)bq_g[0] + (double)bcq_g[0];
  double sa[4] = {0,0,0,0}, ta[4] = {0,0,0,0};
  for (int d = 0; d < 256; ++d){
    double cd = (double)cS[i][d];
    double cw1 = cd * (double)wS[2][d];
    double cw2 = cd * (double)wS[5][d];
    #pragma unroll
    for (int m = 0; m < 4; ++m){
      double qv = (double)qS[js + m * 8][d];
      sa[m] += cw1 * qv;
      ta[m] += cw2 * qv;
    }
  }
  {
    double cwv = cwS[i];
    double s[4], mx = -1e300;
    #pragma unroll
    for (int m = 0; m < 4; ++m){
      s[m] = sa[m] + cwv + qwS[js + m * 8] + bsum;
      mx = fmax(mx, s[m]);
    }
    #pragma unroll
    for (int m = 1; m < 8; m <<= 1) mx = fmax(mx, __shfl_xor(mx, m));
    double esum = 0, eacc = 0;
    #pragma unroll
    for (int m = 0; m < 4; ++m){
      double e = exp(s[m] - mx);
      esum += e;
      eacc += e * (qzS[js + m * 8] + ta[m]);
    }
    #pragma unroll
    for (int m = 1; m < 8; m <<= 1){
      esum += __shfl_xor(esum, m);
      eacc += __shfl_xor(eacc, m);
    }
    if (js == 0){ paS[i] = eacc / esum; smaxS[i] = mx; }
  }
  __syncthreads();
  if (tid < 32){
    double v = smaxS[tid];
    double m2 = v;
    #pragma unroll
    for (int m = 1; m < 32; m <<= 1) m2 = fmax(m2, __shfl_xor(m2, m));
    double e = exp(v - m2), ssum = e;
    #pragma unroll
    for (int m = 1; m < 32; m <<= 1) ssum += __shfl_xor(ssum, m);
    bsmS[tid] = e / ssum;
  }
  __syncthreads();
  {
    double a = 0;
    for (int ii = 0; ii < 32; ++ii) a += bsmS[ii] * (double)cS[ii][tid];
    q2cS[tid] = a;
  }
  __syncthreads();
  {
    double t1 = 0, t4 = 0;
    for (int k = 0; k < 32; ++k){
      int d = js * 32 + k;
      double cd = (double)cS[i][d];
      t1 += cd * (double)wS[3][d];
      t4 += cd * q2cS[d] * (double)wS[6][d];
    }
    #pragma unroll
    for (int m = 1; m < 8; m <<= 1){
      t1 += __shfl_xor(t1, m);
      t4 += __shfl_xor(t4, m);
    }
    if (js == 0)
      pOut[((size_t)pass * 64 + b) * 32 + i] = t1 + paS[i] + t4 + (double)bz_g[0];
  }
}

// ---------------- combine p1/p2 -> score, softmax, scatter ----------------
__global__ __launch_bounds__(64) void k_att2(const double* __restrict__ pOut,
                                             const float* __restrict__ wp1_g, const float* __restrict__ bp1_g,
                                             const float* __restrict__ wp2_g, const float* __restrict__ bp2_g,
                                             const int* __restrict__ cand,
                                             float* __restrict__ out){
  int b = blockIdx.x, tid = threadIdx.x;
  if (tid >= 32) return;
  double p1 = pOut[(size_t)b * 32 + tid];
  double p2 = pOut[(size_t)(64 + b) * 32 + tid];
  double sc = (double)wp1_g[0] * p1 + (double)bp1_g[0]
            + (double)wp2_g[0] * p2 + (double)bp2_g[0];
  double mx = sc, rs = sc;
  #pragma unroll
  for (int m = 1; m < 32; m <<= 1){
    mx = fmax(mx, __shfl_xor(mx, m));
    rs += __shfl_xor(rs, m);
  }
  double e = exp(sc - mx), es = e;
  #pragma unroll
  for (int m = 1; m < 32; m <<= 1) es += __shfl_xor(es, m);
  int col = cand[b * 32 + tid];
  out[(size_t)b * 2048 + col] = (float)sc;
  out[131072 + (size_t)b * 2048 + col] = (float)(e / es);
  out[262144 + (size_t)b * 2048 + col] = (float)(sc / rs);
}

// ---------------------------------------------------------------------------
extern "C" void kernel_launch(void* const* d_in, const int* in_sizes, int n_in,
                              void* d_out, int out_size, void* d_ws, size_t ws_size,
                              hipStream_t stream) {
  const int* title_v = (const int*)d_in[0];
  const int* body_v  = (const int*)d_in[1];
  const int* ctx_v   = (const int*)d_in[3];
  const int* doc_v   = (const int*)d_in[4];
  const int* cand    = (const int*)d_in[5];
  const float* emb   = (const float*)d_in[6];
  const float* convw = (const float*)d_in[7];
  const float* convb = (const float*)d_in[8];
  const float* WihF  = (const float*)d_in[9];
  const float* WhhF  = (const float*)d_in[10];
  const float* bihF  = (const float*)d_in[11];
  const float* bhhF  = (const float*)d_in[12];
  const float* WihB  = (const float*)d_in[13];
  const float* WhhB  = (const float*)d_in[14];
  const float* bihB  = (const float*)d_in[15];
  const float* bhhB  = (const float*)d_in[16];
  float* out = (float*)d_out;

  const size_t CONTRIB_B = (size_t)5056 * 2560 * 2;     // 25,886,720 (fp16)
  char* base = (char*)d_ws;
  if (ws_size < 60325888) return;
  __half* contrib = (__half*)base;
  float* featDoc = (float*)(base + CONTRIB_B + (size_t)4160 * 512 * 4);   // 34,406,400

  // dedup buffers (flags now live in LDS of k_markcompact)
  int* nUsed = (int*)(base + DEDUP_B);
  int* list  = (int*)(base + DEDUP_B + 256);

  // fp16 GEMM / recurrence inputs
  _Float16* A_h  = (_Float16*)(base + AH_B);            // contrib GEMM A (dead after k_contrib)
  _Float16* B_h  = (_Float16*)(base + BH_B);            // contrib GEMM B (dead after k_contrib)
  _Float16* A_hp = (_Float16*)(base + AHP_B);           // proj GEMM A (written by conv epilogue)
  _Float16* B_hp = (_Float16*)(base + BHP_B);           // proj GEMM B
  _Float16* WhhH = (_Float16*)(base + WHH_B);           // recurrence weights fp16

  // post-conv aliases (contrib dead after convs)
  float*  preAll = (float*)(base + 2097152);            // -> 19,202,048
  float*  hT     = (float*)(base + 19202048);           // 2,097,152 each (fp32)
  float*  hB     = (float*)(base + 21299200);
  float*  hC     = (float*)(base + 23396352);
  float*  hD     = (float*)(base + 25493504);           // 32,768
  double* pOut   = (double*)(base + 25526272);          // 32,768 -> ends 25,559,040

  k_prep<<<4096, 256, 0, stream>>>((unsigned int*)out, out_size, featDoc,
                                   emb, A_h, convw, B_h, WihF, WihB, B_hp,
                                   WhhF, WhhB, WhhH);
  k_markcompact<<<1, 1024, 0, stream>>>(cand, nUsed, list);
  k_contrib<<<dim3(79, 20), 256, 0, stream>>>(A_h, B_h, contrib);

  k_conv<<<33312, 256, 0, stream>>>(title_v, body_v, ctx_v, doc_v, contrib, convb,
                                    A_hp, featDoc, list, nUsed);
  k_featTail<<<128, 256, 0, stream>>>(featDoc, A_hp);

  k_proj<<<dim3(66, 4, 2), 256, 0, stream>>>(A_hp, B_hp, bihF, bhhF, bihB, bhhB, preAll);
  k_recur<<<dim3(193, 2), 512, 0, stream>>>(preAll, WhhH, cand, hT, hB, hC, hD);
  k_att1<<<dim3(64, 2), 256, 0, stream>>>(hC, hT, hD, hB,
                                (const float*)d_in[17], (const float*)d_in[18],
                                (const float*)d_in[19], (const float*)d_in[20],
                                (const float*)d_in[21], (const float*)d_in[22],
                                (const float*)d_in[23], (const float*)d_in[24],
                                pOut);
  k_att2<<<64, 64, 0, stream>>>(pOut,
                                (const float*)d_in[25], (const float*)d_in[26],
                                (const float*)d_in[27], (const float*)d_in[28],
                                cand, out);
}